// Round 18
// baseline (1343.051 us; speedup 1.0000x reference)
//
#include <hip/hip_runtime.h>
#include <stdint.h>

#define NB 512   // batch
#define NT 32    // time steps
#define NIN 8    // input feats
#define NIN1 9   // + y_prev
#define NH 64    // hidden
#define NP 256   // particles
#define NTHR 512 // 8 waves: wave wq owns gate-rows r' in [32wq, 32wq+32)
#define HROW 68  // f16 row stride: 136 B = 34 dwords -> 2-way bank alias (free)

typedef __attribute__((ext_vector_type(8))) _Float16 f16x8;
typedef __attribute__((ext_vector_type(4))) float f32x4;

struct FKeys { uint32_t a[NT]; uint32_t b[NT]; };

// ---------------- Threefry-2x32-20 (exact JAX semantics) ----------------
__host__ __device__ __forceinline__ void tfr(uint32_t& x0, uint32_t& x1, int r) {
  x0 += x1; x1 = (x1 << r) | (x1 >> (32 - r)); x1 ^= x0;
}

__host__ __device__ __forceinline__ void threefry2x32(uint32_t k0, uint32_t k1,
                                                      uint32_t& x0, uint32_t& x1) {
  uint32_t k2 = k0 ^ k1 ^ 0x1BD11BDAu;
  x0 += k0; x1 += k1;
  tfr(x0,x1,13); tfr(x0,x1,15); tfr(x0,x1,26); tfr(x0,x1,6);
  x0 += k1; x1 += k2 + 1u;
  tfr(x0,x1,17); tfr(x0,x1,29); tfr(x0,x1,16); tfr(x0,x1,24);
  x0 += k2; x1 += k0 + 2u;
  tfr(x0,x1,13); tfr(x0,x1,15); tfr(x0,x1,26); tfr(x0,x1,6);
  x0 += k0; x1 += k1 + 3u;
  tfr(x0,x1,17); tfr(x0,x1,29); tfr(x0,x1,16); tfr(x0,x1,24);
  x0 += k1; x1 += k2 + 4u;
  tfr(x0,x1,13); tfr(x0,x1,15); tfr(x0,x1,26); tfr(x0,x1,6);
  x0 += k2; x1 += k0 + 5u;
}

// bits -> uniform -> sqrt(2)*erfinv  (XLA f32 path; __logf variant validated
// R11 at absmax 0.5).
__device__ __forceinline__ float normal_from_bits(uint32_t bits) {
  float f = __uint_as_float((bits >> 9) | 0x3f800000u) - 1.0f;
  const float lo = -0.99999994f;
  float u = fmaxf(lo, fmaf(f, 2.0f, lo));
  float w = -__logf(fmaf(-u, u, 1.0f));
  float p;
  if (w < 5.0f) {
    w -= 2.5f;
    p = 2.81022636e-08f;
    p = fmaf(p, w, 3.43273939e-07f);
    p = fmaf(p, w, -3.5233877e-06f);
    p = fmaf(p, w, -4.39150654e-06f);
    p = fmaf(p, w, 0.00021858087f);
    p = fmaf(p, w, -0.00125372503f);
    p = fmaf(p, w, -0.00417768164f);
    p = fmaf(p, w, 0.246640727f);
    p = fmaf(p, w, 1.50140941f);
  } else {
    w = sqrtf(w) - 3.0f;
    p = -0.000200214257f;
    p = fmaf(p, w, 0.000100950558f);
    p = fmaf(p, w, 0.00134934322f);
    p = fmaf(p, w, -0.00367342844f);
    p = fmaf(p, w, 0.00573950773f);
    p = fmaf(p, w, -0.0076224613f);
    p = fmaf(p, w, 0.00943887047f);
    p = fmaf(p, w, 1.00167406f);
    p = fmaf(p, w, 2.83297682f);
  }
  return 1.41421356f * (p * u);
}

__device__ __forceinline__ float frcp(float x) { return __builtin_amdgcn_rcpf(x); }
__device__ __forceinline__ float fsigmoid(float x) { return frcp(1.0f + __expf(-x)); }
__device__ __forceinline__ float ftanh(float x) { return 1.0f - 2.0f * frcp(1.0f + __expf(2.0f * x)); }

// f32 -> f16 bits (RNE)
__device__ __forceinline__ uint32_t pack_f16(float x) {
  union { _Float16 h; uint16_t u; } c;
  c.h = (_Float16)x;
  return (uint32_t)c.u;
}
// packed f16 pair access (compile-time hi flag)
__device__ __forceinline__ float unpk_f16(uint32_t w, int hi) {
  union { _Float16 h; uint16_t u; } c;
  c.u = hi ? (uint16_t)(w >> 16) : (uint16_t)(w & 0xffffu);
  return (float)c.h;
}

// 8B-aligned LDS f16x8 load (two ds_read_b64)
__device__ __forceinline__ f16x8 ld8h(const _Float16* p) {
  union { f16x8 v; uint64_t q[2]; } u;
  u.q[0] = *(const uint64_t*)(p);
  u.q[1] = *(const uint64_t*)(p + 4);
  return u.v;
}

// ---------------- main kernel: one block (512 thr) per batch elem ----------------
// 16x16x32 MFMA variant: D-block = 16 gate-rows (4 k-groups) x 16 particles.
// Lane l (lrow=l>>4&3, lcol=l&15) gets all 4 gates of cell (k = 8wq+4kg2+lrow,
// p = 16pt8+lcol [+128]) in a 4-register accumulator. A = W' rows r'=32wq+16kg2+lcol,
// elems j = kt*32+lrow*8+e (mirrors the verified 32x32 conventions).
// Single-f16 h, h0 unsorted staging + phase-F permute copy, c packed f16 pairs.
__global__ __launch_bounds__(NTHR, 2)
void pf_main(const float* __restrict__ input_data, const float* __restrict__ y_prev,
             const float* __restrict__ Wv, const float* __restrict__ bv,
             const float* __restrict__ W_ih, const float* __restrict__ W_hh,
             const float* __restrict__ b_ih, const float* __restrict__ b_hh,
             const float* __restrict__ Wp, const float* __restrict__ bp,
             const float* __restrict__ Wf, const float* __restrict__ bf,
             float* __restrict__ out, float* __restrict__ gw,
             FKeys fk)
{
  __shared__ __align__(16) _Float16 h1_s[NP * HROW];  // 34.8 KB sorted h
  __shared__ __align__(16) _Float16 h0_s[NP * HROW];  // 34.8 KB unsorted new h
  __shared__ __align__(16) float xg_s[NP];
  __shared__ __align__(16) float proj_s[NP];
  __shared__ float lp_s[NP];
  __shared__ float wsum_s[NP];
  __shared__ int   rankP_s[2 * NP];
  __shared__ float hsum_s[NH];
  __shared__ float std_s[NH];
  __shared__ float xs_s[16];

  const int tid  = threadIdx.x;
  const int b    = blockIdx.x;
  const int lane = tid & 63;
  const int wq   = tid >> 6;          // wave 0..7: gate-row group
  const int lrow = (lane >> 4) & 3;   // 0..3
  const int lcol = lane & 15;         // 0..15

  for (int i = tid; i < NP * HROW; i += NTHR) h1_s[i] = (_Float16)0.0f;
  if (tid < NP) wsum_s[tid] = 0.0f;
  if (tid < NH) hsum_s[tid] = 0.0f;

  const float bf0 = bf[0];
  const float bp0 = bp[0];
  const uint32_t bsh = (uint32_t)b << 6;

  // A fragments (single f16), loaded ONCE: w1f[kg2][kt]
  f16x8 w1f[2][2];
  #pragma unroll
  for (int kg2 = 0; kg2 < 2; ++kg2) {
    const int rpr  = 32 * wq + 16 * kg2 + lcol;
    const int orig = (rpr & 3) * NH + (rpr >> 2);
    #pragma unroll
    for (int kt = 0; kt < 2; ++kt) {
      #pragma unroll
      for (int e = 0; e < 8; ++e)
        w1f[kg2][kt][e] = (_Float16)W_hh[orig * NH + kt * 32 + lrow * 8 + e];
    }
  }

  float wf2[2], wp2[2];
  #pragma unroll
  for (int kg2 = 0; kg2 < 2; ++kg2) {
    const int k = 8 * wq + 4 * kg2 + lrow;
    wf2[kg2] = Wf[k];
    wp2[kg2] = Wp[k];
  }

  // c state packed as f16 pairs (p, p+128): [kg2][pt8], never sorted
  uint32_t cp[2][8];
  #pragma unroll
  for (int kg2 = 0; kg2 < 2; ++kg2)
    #pragma unroll
    for (int j = 0; j < 8; ++j) cp[kg2][j] = 0u;

  auto finalize_init = [&]() {
    if (tid < NH) {
      float v = bv[tid];
      const float* wvr = Wv + tid * (NIN1 + NH);
      #pragma unroll
      for (int i = 0; i < NIN1; ++i) v = fmaf(xs_s[i], wvr[i], v);
      #pragma unroll
      for (int k = 0; k < NH; ++k)
        v = fmaf(hsum_s[k] * (1.0f / NP), wvr[NIN1 + k], v);
      std_s[tid] = fmaxf(v, 0.0f) + log1pf(expf(-fabsf(v)));   // softplus, libm exact
    }
    if (tid < NP) {
      const int orow = (tid & 3) * NH + (tid >> 2);
      float a = b_ih[orow] + b_hh[orow];
      const float* wr = W_ih + orow * NIN1;
      #pragma unroll
      for (int i = 0; i < NIN1; ++i) a = fmaf(xs_s[i], wr[i], a);
      xg_s[tid] = a;
      proj_s[tid] = bf0;
      float xp = bp0;
      #pragma unroll
      for (int i = 0; i < NIN1; ++i) xp = fmaf(xs_s[i], Wp[NH + i], xp);
      lp_s[tid] = xp;
    }
  };

  if (tid < NIN) xs_s[tid] = input_data[(b * NT + 0) * NIN + tid];
  if (tid == NIN) xs_s[NIN] = y_prev[b * NT + 0];
  __syncthreads();
  finalize_init();
  __syncthreads();

  for (int t = 0; t < NT; ++t) {
    // ================= phase A: MFMA + elementwise (+ xs_{t+1} prefetch) ========
    if (tid < 16 && t + 1 < NT) {
      if (tid < NIN) xs_s[tid] = input_data[(b * NT + t + 1) * NIN + tid];
      if (tid == NIN) xs_s[NIN] = y_prev[b * NT + t + 1];
    }

    float std2[2];
    #pragma unroll
    for (int kg2 = 0; kg2 < 2; ++kg2) std2[kg2] = std_s[8 * wq + 4 * kg2 + lrow];

    const uint32_t fk0 = fk.a[t], fk1 = fk.b[t];
    float hs2[2] = {0.0f, 0.0f};

    #pragma unroll
    for (int pt8 = 0; pt8 < 8; ++pt8) {
      const int p = 16 * pt8 + lcol;
      const f16x8 bA0 = ld8h(&h1_s[p * HROW + lrow * 8]);
      const f16x8 bA1 = ld8h(&h1_s[p * HROW + 32 + lrow * 8]);
      const f16x8 bB0 = ld8h(&h1_s[(p + 128) * HROW + lrow * 8]);
      const f16x8 bB1 = ld8h(&h1_s[(p + 128) * HROW + 32 + lrow * 8]);

      float plp = 0.0f, lpp = 0.0f, plp1 = 0.0f, lpp1 = 0.0f;
      #pragma unroll
      for (int kg2 = 0; kg2 < 2; ++kg2) {
        const int k = 8 * wq + 4 * kg2 + lrow;
        const float4 xgv = *(const float4*)&xg_s[32 * wq + 16 * kg2 + 4 * lrow];
        f32x4 accA, accB;
        accA[0] = xgv.x; accA[1] = xgv.y; accA[2] = xgv.z; accA[3] = xgv.w;
        accB = accA;
        accA = __builtin_amdgcn_mfma_f32_16x16x32_f16(w1f[kg2][0], bA0, accA, 0, 0, 0);
        accB = __builtin_amdgcn_mfma_f32_16x16x32_f16(w1f[kg2][0], bB0, accB, 0, 0, 0);
        accA = __builtin_amdgcn_mfma_f32_16x16x32_f16(w1f[kg2][1], bA1, accA, 0, 0, 0);
        accB = __builtin_amdgcn_mfma_f32_16x16x32_f16(w1f[kg2][1], bB1, accB, 0, 0, 0);
        // ---- cell (k, p): gates i,f,g,o = accA[0..3] ----
        float si = fsigmoid(accA[0]);
        float sf = fsigmoid(accA[1]);
        float so = fsigmoid(accA[3]);
        float cold = unpk_f16(cp[kg2][pt8], 0);
        float cn = sf * cold + si * ftanh(accA[2]);
        float hlA = so * ftanh(cn);
        // ---- cell (k, p+128) ----
        float si2 = fsigmoid(accB[0]);
        float sf2 = fsigmoid(accB[1]);
        float so2 = fsigmoid(accB[3]);
        float cold2 = unpk_f16(cp[kg2][pt8], 1);
        float cn2 = sf2 * cold2 + si2 * ftanh(accB[2]);
        cp[kg2][pt8] = pack_f16(cn) | (pack_f16(cn2) << 16);
        float hlB = so2 * ftanh(cn2);
        // ---- shared threefry: pair (p, p+128) ----
        uint32_t x0 = ((uint32_t)p << 15) | bsh | (uint32_t)k;
        uint32_t x1 = x0 + (1u << 22);
        threefry2x32(fk0, fk1, x0, x1);
        float hA = fmaf(normal_from_bits(x0), std2[kg2], hlA);
        float hB = fmaf(normal_from_bits(x1), std2[kg2], hlB);
        hs2[kg2] += hA + hB;
        plp  = fmaf(hA, wf2[kg2], plp);  lpp  = fmaf(hA, wp2[kg2], lpp);
        plp1 = fmaf(hB, wf2[kg2], plp1); lpp1 = fmaf(hB, wp2[kg2], lpp1);
        h0_s[p * HROW + k] = (_Float16)hA;
        h0_s[(p + 128) * HROW + k] = (_Float16)hB;
      }
      // reduce over the 4 lrow groups sharing each particle column
      plp  += __shfl_xor(plp, 16, 64);  plp  += __shfl_xor(plp, 32, 64);
      lpp  += __shfl_xor(lpp, 16, 64);  lpp  += __shfl_xor(lpp, 32, 64);
      plp1 += __shfl_xor(plp1, 16, 64); plp1 += __shfl_xor(plp1, 32, 64);
      lpp1 += __shfl_xor(lpp1, 16, 64); lpp1 += __shfl_xor(lpp1, 32, 64);
      if (lane < 16) {
        atomicAdd(&proj_s[p], plp);
        atomicAdd(&lp_s[p], lpp);
        atomicAdd(&proj_s[p + 128], plp1);
        atomicAdd(&lp_s[p + 128], lpp1);
      }
    }
    // hsum: reduce over the 16 lcol lanes sharing each k
    #pragma unroll
    for (int kg2 = 0; kg2 < 2; ++kg2) {
      float s = hs2[kg2];
      s += __shfl_xor(s, 1, 64); s += __shfl_xor(s, 2, 64);
      s += __shfl_xor(s, 4, 64); s += __shfl_xor(s, 8, 64);
      if (lcol == 0) hsum_s[8 * wq + 4 * kg2 + lrow] = s;
    }
    __syncthreads();   // b1: h1 reads + h0 writes + proj/lp atomics + xs_next done

    // ================= phase R: split stable-rank (512 half-jobs) =================
    {
      const int ph = tid & (NP - 1);
      const int hh = tid >> 8;
      const float pv = proj_s[ph];
      int rk = 0;
      const float4* c4 = (const float4*)proj_s;
      #pragma unroll 8
      for (int q4 = 32 * hh; q4 < 32 * hh + 32; ++q4) {
        float4 v = c4[q4];
        int qb = q4 * 4;
        rk += (v.x < pv || (v.x == pv && qb + 0 < ph)) ? 1 : 0;
        rk += (v.y < pv || (v.y == pv && qb + 1 < ph)) ? 1 : 0;
        rk += (v.z < pv || (v.z == pv && qb + 2 < ph)) ? 1 : 0;
        rk += (v.w < pv || (v.w == pv && qb + 3 < ph)) ? 1 : 0;
      }
      rankP_s[hh * NP + ph] = rk;
    }
    __syncthreads();   // b2: rank partials ready

    // ================= phase F: copy h0[p] -> h1[rank[p]] + wsum + next init ====
    {
      const int ph = tid & (NP - 1);
      const int hh = tid >> 8;
      const int rank = rankP_s[ph] + rankP_s[NP + ph];
      const uint64_t* s = (const uint64_t*)&h0_s[ph * HROW + 32 * hh];
      const uint64_t v0 = s[0], v1 = s[1], v2 = s[2], v3 = s[3];
      uint64_t* d = (uint64_t*)&h1_s[rank * HROW + 32 * hh];
      d[0] = v0; d[1] = v1; d[2] = v2; d[3] = v3;
      if (hh == 0) wsum_s[rank] += __expf(lp_s[ph]);   // permutation -> race-free
    }
    finalize_init();
    __syncthreads();   // b3 (loop end): h writes + next-step init visible
  }

  // ---- epilogue: y_pred[b] = mean_p(h_fin) @ Wf + bf ----
  if (tid < NH) {
    float hm = hsum_s[tid] * (1.0f / NP);
    float contrib = hm * Wf[tid];
    contrib += __shfl_xor(contrib, 32, 64);
    contrib += __shfl_xor(contrib, 16, 64);
    contrib += __shfl_xor(contrib, 8, 64);
    contrib += __shfl_xor(contrib, 4, 64);
    contrib += __shfl_xor(contrib, 2, 64);
    contrib += __shfl_xor(contrib, 1, 64);
    if (tid == 0) out[b] = contrib + bf0;
  }
  if (tid < NP) gw[(size_t)tid * NB + b] = wsum_s[tid];
}

// weights[i] = (1/256) * sum_{j<256} gw[(i>>1)*512 + (i&1)*256 + j]
__global__ __launch_bounds__(64, 1)
void pf_weights(const float* __restrict__ gw, float* __restrict__ out) {
  int i = blockIdx.x;
  int lane = threadIdx.x;
  const float* src = gw + ((size_t)(i >> 1)) * NB + (size_t)(i & 1) * NP;
  float4 v = ((const float4*)src)[lane];
  float s = (v.x + v.y) + (v.z + v.w);
  s += __shfl_xor(s, 32, 64);
  s += __shfl_xor(s, 16, 64);
  s += __shfl_xor(s, 8, 64);
  s += __shfl_xor(s, 4, 64);
  s += __shfl_xor(s, 2, 64);
  s += __shfl_xor(s, 1, 64);
  if (lane == 0) out[NB + i] = s * (1.0f / NP);
}

extern "C" void kernel_launch(void* const* d_in, const int* in_sizes, int n_in,
                              void* d_out, int out_size, void* d_ws, size_t ws_size,
                              hipStream_t stream) {
  (void)in_sizes; (void)n_in; (void)out_size; (void)ws_size;
  const float* input_data = (const float*)d_in[0];
  const float* y_prev     = (const float*)d_in[1];
  const float* Wv         = (const float*)d_in[2];
  const float* bv         = (const float*)d_in[3];
  const float* W_ih       = (const float*)d_in[4];
  const float* W_hh       = (const float*)d_in[5];
  const float* b_ih       = (const float*)d_in[6];
  const float* b_hh       = (const float*)d_in[7];
  const float* Wp         = (const float*)d_in[8];
  const float* bp         = (const float*)d_in[9];
  const float* Wf         = (const float*)d_in[10];
  const float* bf         = (const float*)d_in[11];
  float* out = (float*)d_out;
  float* gw  = (float*)d_ws;                           // [P][B] f32 = 512 KB

  FKeys fk;
  for (int t = 0; t < NT; ++t) {
    uint32_t x0 = 0u, x1 = (uint32_t)t;
    threefry2x32(0u, 1234u, x0, x1);
    fk.a[t] = x0; fk.b[t] = x1;
  }

  pf_main<<<dim3(NB), dim3(NTHR), 0, stream>>>(
      input_data, y_prev, Wv, bv, W_ih, W_hh, b_ih, b_hh, Wp, bp, Wf, bf,
      out, gw, fk);
  pf_weights<<<dim3(NB), dim3(64), 0, stream>>>(gw, out);
}

// Round 19
// 1335.733 us; speedup vs baseline: 1.0055x; 1.0055x over previous
//
#include <hip/hip_runtime.h>
#include <stdint.h>

#define NB 512   // batch
#define NT 32    // time steps
#define NIN 8    // input feats
#define NIN1 9   // + y_prev
#define NH 64    // hidden
#define NP 256   // particles
#define NTHR 512 // 8 waves: wave wq owns gate-rows r' in [32wq, 32wq+32)
#define HROW 68  // f16 row stride: 136 B = 34 dwords -> 2-way bank alias (free)

typedef __attribute__((ext_vector_type(8))) _Float16 f16x8;
typedef __attribute__((ext_vector_type(4))) float f32x4;

struct FKeys { uint32_t a[NT]; uint32_t b[NT]; };

// ---------------- Threefry-2x32-20 (exact JAX semantics) ----------------
__host__ __device__ __forceinline__ void tfr(uint32_t& x0, uint32_t& x1, int r) {
  x0 += x1; x1 = (x1 << r) | (x1 >> (32 - r)); x1 ^= x0;
}

__host__ __device__ __forceinline__ void threefry2x32(uint32_t k0, uint32_t k1,
                                                      uint32_t& x0, uint32_t& x1) {
  uint32_t k2 = k0 ^ k1 ^ 0x1BD11BDAu;
  x0 += k0; x1 += k1;
  tfr(x0,x1,13); tfr(x0,x1,15); tfr(x0,x1,26); tfr(x0,x1,6);
  x0 += k1; x1 += k2 + 1u;
  tfr(x0,x1,17); tfr(x0,x1,29); tfr(x0,x1,16); tfr(x0,x1,24);
  x0 += k2; x1 += k0 + 2u;
  tfr(x0,x1,13); tfr(x0,x1,15); tfr(x0,x1,26); tfr(x0,x1,6);
  x0 += k0; x1 += k1 + 3u;
  tfr(x0,x1,17); tfr(x0,x1,29); tfr(x0,x1,16); tfr(x0,x1,24);
  x0 += k1; x1 += k2 + 4u;
  tfr(x0,x1,13); tfr(x0,x1,15); tfr(x0,x1,26); tfr(x0,x1,6);
  x0 += k2; x1 += k0 + 5u;
}

// bits -> uniform -> sqrt(2)*erfinv  (XLA f32 path; __logf variant validated
// R11 at absmax 0.5).
__device__ __forceinline__ float normal_from_bits(uint32_t bits) {
  float f = __uint_as_float((bits >> 9) | 0x3f800000u) - 1.0f;
  const float lo = -0.99999994f;
  float u = fmaxf(lo, fmaf(f, 2.0f, lo));
  float w = -__logf(fmaf(-u, u, 1.0f));
  float p;
  if (w < 5.0f) {
    w -= 2.5f;
    p = 2.81022636e-08f;
    p = fmaf(p, w, 3.43273939e-07f);
    p = fmaf(p, w, -3.5233877e-06f);
    p = fmaf(p, w, -4.39150654e-06f);
    p = fmaf(p, w, 0.00021858087f);
    p = fmaf(p, w, -0.00125372503f);
    p = fmaf(p, w, -0.00417768164f);
    p = fmaf(p, w, 0.246640727f);
    p = fmaf(p, w, 1.50140941f);
  } else {
    w = sqrtf(w) - 3.0f;
    p = -0.000200214257f;
    p = fmaf(p, w, 0.000100950558f);
    p = fmaf(p, w, 0.00134934322f);
    p = fmaf(p, w, -0.00367342844f);
    p = fmaf(p, w, 0.00573950773f);
    p = fmaf(p, w, -0.0076224613f);
    p = fmaf(p, w, 0.00943887047f);
    p = fmaf(p, w, 1.00167406f);
    p = fmaf(p, w, 2.83297682f);
  }
  return 1.41421356f * (p * u);
}

__device__ __forceinline__ float frcp(float x) { return __builtin_amdgcn_rcpf(x); }
__device__ __forceinline__ float fsigmoid(float x) { return frcp(1.0f + __expf(-x)); }
__device__ __forceinline__ float ftanh(float x) { return 1.0f - 2.0f * frcp(1.0f + __expf(2.0f * x)); }

// f32 -> f16 bits (RNE)
__device__ __forceinline__ uint32_t pack_f16(float x) {
  union { _Float16 h; uint16_t u; } c;
  c.h = (_Float16)x;
  return (uint32_t)c.u;
}
__device__ __forceinline__ _Float16 bits_to_h(uint16_t u) {
  union { _Float16 h; uint16_t u; } c;
  c.u = u;
  return c.h;
}

// 8B-aligned LDS f16x8 load (two ds_read_b64)
__device__ __forceinline__ f16x8 ld8h(const _Float16* p) {
  union { f16x8 v; uint64_t q[2]; } u;
  u.q[0] = *(const uint64_t*)(p);
  u.q[1] = *(const uint64_t*)(p + 4);
  return u.v;
}

// ---------------- main kernel: one block (512 thr) per batch elem ----------------
// 16x16x32 MFMA; single h1_s LDS buffer (~42 KB total) so 2 blocks/CU fit the
// LDS pool. New h staged in 16 packed u32 regs (shp), scattered at ranked rows
// in phase F. c state lives in GLOBAL f32 (coalesced 256B/wave groups, L2/L3-
// resident), zero at t==0 via guard (harness poison never read).
__global__ __launch_bounds__(NTHR, 2)
void pf_main(const float* __restrict__ input_data, const float* __restrict__ y_prev,
             const float* __restrict__ Wv, const float* __restrict__ bv,
             const float* __restrict__ W_ih, const float* __restrict__ W_hh,
             const float* __restrict__ b_ih, const float* __restrict__ b_hh,
             const float* __restrict__ Wp, const float* __restrict__ bp,
             const float* __restrict__ Wf, const float* __restrict__ bf,
             float* __restrict__ out, float* __restrict__ gw, float* __restrict__ cg,
             FKeys fk)
{
  __shared__ __align__(16) _Float16 h1_s[NP * HROW];  // 34.8 KB sorted h
  __shared__ __align__(16) float xg_s[NP];
  __shared__ __align__(16) float proj_s[NP];
  __shared__ float lp_s[NP];
  __shared__ float wsum_s[NP];
  __shared__ int   rankP_s[2 * NP];
  __shared__ float hsum_s[NH];
  __shared__ float std_s[NH];
  __shared__ float xs_s[16];

  const int tid  = threadIdx.x;
  const int b    = blockIdx.x;
  const int lane = tid & 63;
  const int wq   = tid >> 6;          // wave 0..7: gate-row group
  const int lrow = (lane >> 4) & 3;   // 0..3
  const int lcol = lane & 15;         // 0..15

  for (int i = tid; i < NP * HROW; i += NTHR) h1_s[i] = (_Float16)0.0f;
  if (tid < NP) wsum_s[tid] = 0.0f;
  if (tid < NH) hsum_s[tid] = 0.0f;

  const float bf0 = bf[0];
  const float bp0 = bp[0];
  const uint32_t bsh = (uint32_t)b << 6;

  // A fragments (single f16), loaded ONCE: w1f[kg2][kt]
  f16x8 w1f[2][2];
  #pragma unroll
  for (int kg2 = 0; kg2 < 2; ++kg2) {
    const int rpr  = 32 * wq + 16 * kg2 + lcol;
    const int orig = (rpr & 3) * NH + (rpr >> 2);
    #pragma unroll
    for (int kt = 0; kt < 2; ++kt) {
      #pragma unroll
      for (int e = 0; e < 8; ++e)
        w1f[kg2][kt][e] = (_Float16)W_hh[orig * NH + kt * 32 + lrow * 8 + e];
    }
  }

  float wf2[2], wp2[2];
  #pragma unroll
  for (int kg2 = 0; kg2 < 2; ++kg2) {
    const int k = 8 * wq + 4 * kg2 + lrow;
    wf2[kg2] = Wf[k];
    wp2[kg2] = Wp[k];
  }

  // global c base for this thread's wave group: cells addressed per (kg2, pt8, ab)
  float* cgw = cg + ((size_t)b * 8 + wq) * (2 * 8 * 128) + lane;

  auto finalize_init = [&]() {
    if (tid < NH) {
      float v = bv[tid];
      const float* wvr = Wv + tid * (NIN1 + NH);
      #pragma unroll
      for (int i = 0; i < NIN1; ++i) v = fmaf(xs_s[i], wvr[i], v);
      #pragma unroll
      for (int k = 0; k < NH; ++k)
        v = fmaf(hsum_s[k] * (1.0f / NP), wvr[NIN1 + k], v);
      std_s[tid] = fmaxf(v, 0.0f) + log1pf(expf(-fabsf(v)));   // softplus, libm exact
    }
    if (tid < NP) {
      const int orow = (tid & 3) * NH + (tid >> 2);
      float a = b_ih[orow] + b_hh[orow];
      const float* wr = W_ih + orow * NIN1;
      #pragma unroll
      for (int i = 0; i < NIN1; ++i) a = fmaf(xs_s[i], wr[i], a);
      xg_s[tid] = a;
      proj_s[tid] = bf0;
      float xp = bp0;
      #pragma unroll
      for (int i = 0; i < NIN1; ++i) xp = fmaf(xs_s[i], Wp[NH + i], xp);
      lp_s[tid] = xp;
    }
  };

  if (tid < NIN) xs_s[tid] = input_data[(b * NT + 0) * NIN + tid];
  if (tid == NIN) xs_s[NIN] = y_prev[b * NT + 0];
  __syncthreads();
  finalize_init();
  __syncthreads();

  for (int t = 0; t < NT; ++t) {
    // ================= phase A: MFMA + elementwise (+ xs_{t+1} prefetch) ========
    if (tid < 16 && t + 1 < NT) {
      if (tid < NIN) xs_s[tid] = input_data[(b * NT + t + 1) * NIN + tid];
      if (tid == NIN) xs_s[NIN] = y_prev[b * NT + t + 1];
    }

    float std2[2];
    #pragma unroll
    for (int kg2 = 0; kg2 < 2; ++kg2) std2[kg2] = std_s[8 * wq + 4 * kg2 + lrow];

    const uint32_t fk0 = fk.a[t], fk1 = fk.b[t];
    const bool t0 = (t == 0);
    float hs2[2] = {0.0f, 0.0f};
    uint32_t shp[2][8];   // packed new h: lo = (k,p), hi = (k,p+128)

    #pragma unroll
    for (int pt8 = 0; pt8 < 8; ++pt8) {
      const int p = 16 * pt8 + lcol;
      const f16x8 bA0 = ld8h(&h1_s[p * HROW + lrow * 8]);
      const f16x8 bA1 = ld8h(&h1_s[p * HROW + 32 + lrow * 8]);
      const f16x8 bB0 = ld8h(&h1_s[(p + 128) * HROW + lrow * 8]);
      const f16x8 bB1 = ld8h(&h1_s[(p + 128) * HROW + 32 + lrow * 8]);

      float plp = 0.0f, lpp = 0.0f, plp1 = 0.0f, lpp1 = 0.0f;
      #pragma unroll
      for (int kg2 = 0; kg2 < 2; ++kg2) {
        const int k = 8 * wq + 4 * kg2 + lrow;
        float* cptr = cgw + (size_t)(kg2 * 8 + pt8) * 128;
        const float cvA = cptr[0];
        const float cvB = cptr[64];
        const float4 xgv = *(const float4*)&xg_s[32 * wq + 16 * kg2 + 4 * lrow];
        f32x4 accA, accB;
        accA[0] = xgv.x; accA[1] = xgv.y; accA[2] = xgv.z; accA[3] = xgv.w;
        accB = accA;
        accA = __builtin_amdgcn_mfma_f32_16x16x32_f16(w1f[kg2][0], bA0, accA, 0, 0, 0);
        accB = __builtin_amdgcn_mfma_f32_16x16x32_f16(w1f[kg2][0], bB0, accB, 0, 0, 0);
        accA = __builtin_amdgcn_mfma_f32_16x16x32_f16(w1f[kg2][1], bA1, accA, 0, 0, 0);
        accB = __builtin_amdgcn_mfma_f32_16x16x32_f16(w1f[kg2][1], bB1, accB, 0, 0, 0);
        // ---- cell (k, p) ----
        float si = fsigmoid(accA[0]);
        float sf = fsigmoid(accA[1]);
        float so = fsigmoid(accA[3]);
        float cn = sf * (t0 ? 0.0f : cvA) + si * ftanh(accA[2]);
        cptr[0] = cn;
        float hlA = so * ftanh(cn);
        // ---- cell (k, p+128) ----
        float si2 = fsigmoid(accB[0]);
        float sf2 = fsigmoid(accB[1]);
        float so2 = fsigmoid(accB[3]);
        float cn2 = sf2 * (t0 ? 0.0f : cvB) + si2 * ftanh(accB[2]);
        cptr[64] = cn2;
        float hlB = so2 * ftanh(cn2);
        // ---- shared threefry: pair (p, p+128) ----
        uint32_t x0 = ((uint32_t)p << 15) | bsh | (uint32_t)k;
        uint32_t x1 = x0 + (1u << 22);
        threefry2x32(fk0, fk1, x0, x1);
        float hA = fmaf(normal_from_bits(x0), std2[kg2], hlA);
        float hB = fmaf(normal_from_bits(x1), std2[kg2], hlB);
        hs2[kg2] += hA + hB;
        plp  = fmaf(hA, wf2[kg2], plp);  lpp  = fmaf(hA, wp2[kg2], lpp);
        plp1 = fmaf(hB, wf2[kg2], plp1); lpp1 = fmaf(hB, wp2[kg2], lpp1);
        shp[kg2][pt8] = pack_f16(hA) | (pack_f16(hB) << 16);
      }
      // reduce over the 4 lrow groups sharing each particle column
      plp  += __shfl_xor(plp, 16, 64);  plp  += __shfl_xor(plp, 32, 64);
      lpp  += __shfl_xor(lpp, 16, 64);  lpp  += __shfl_xor(lpp, 32, 64);
      plp1 += __shfl_xor(plp1, 16, 64); plp1 += __shfl_xor(plp1, 32, 64);
      lpp1 += __shfl_xor(lpp1, 16, 64); lpp1 += __shfl_xor(lpp1, 32, 64);
      if (lane < 16) {
        atomicAdd(&proj_s[p], plp);
        atomicAdd(&lp_s[p], lpp);
        atomicAdd(&proj_s[p + 128], plp1);
        atomicAdd(&lp_s[p + 128], lpp1);
      }
    }
    // hsum: reduce over the 16 lcol lanes sharing each k
    #pragma unroll
    for (int kg2 = 0; kg2 < 2; ++kg2) {
      float s = hs2[kg2];
      s += __shfl_xor(s, 1, 64); s += __shfl_xor(s, 2, 64);
      s += __shfl_xor(s, 4, 64); s += __shfl_xor(s, 8, 64);
      if (lcol == 0) hsum_s[8 * wq + 4 * kg2 + lrow] = s;
    }
    __syncthreads();   // b1: h1 reads + proj/lp atomics + hsum + xs_next done

    // ================= phase R: split stable-rank (512 half-jobs) =================
    {
      const int ph = tid & (NP - 1);
      const int hh = tid >> 8;
      const float pv = proj_s[ph];
      int rk = 0;
      const float4* c4 = (const float4*)proj_s;
      #pragma unroll 8
      for (int q4 = 32 * hh; q4 < 32 * hh + 32; ++q4) {
        float4 v = c4[q4];
        int qb = q4 * 4;
        rk += (v.x < pv || (v.x == pv && qb + 0 < ph)) ? 1 : 0;
        rk += (v.y < pv || (v.y == pv && qb + 1 < ph)) ? 1 : 0;
        rk += (v.z < pv || (v.z == pv && qb + 2 < ph)) ? 1 : 0;
        rk += (v.w < pv || (v.w == pv && qb + 3 < ph)) ? 1 : 0;
      }
      rankP_s[hh * NP + ph] = rk;
    }
    __syncthreads();   // b2: rank partials ready

    // ================= phase F: scatter shp at ranked rows + wsum + next init ===
    if (tid < NP) {
      const int rank = rankP_s[tid] + rankP_s[NP + tid];
      wsum_s[rank] += __expf(lp_s[tid]);   // ranks form a permutation -> race-free
    }
    #pragma unroll
    for (int kg2 = 0; kg2 < 2; ++kg2) {
      const int k = 8 * wq + 4 * kg2 + lrow;
      #pragma unroll
      for (int pt8 = 0; pt8 < 8; ++pt8) {
        const int p = 16 * pt8 + lcol;
        const int rA = rankP_s[p] + rankP_s[NP + p];
        const int rB = rankP_s[p + 128] + rankP_s[NP + p + 128];
        const uint32_t v = shp[kg2][pt8];
        h1_s[rA * HROW + k] = bits_to_h((uint16_t)(v & 0xffffu));
        h1_s[rB * HROW + k] = bits_to_h((uint16_t)(v >> 16));
      }
    }
    finalize_init();
    __syncthreads();   // b3 (loop end): h writes + next-step init visible
  }

  // ---- epilogue: y_pred[b] = mean_p(h_fin) @ Wf + bf ----
  if (tid < NH) {
    float hm = hsum_s[tid] * (1.0f / NP);
    float contrib = hm * Wf[tid];
    contrib += __shfl_xor(contrib, 32, 64);
    contrib += __shfl_xor(contrib, 16, 64);
    contrib += __shfl_xor(contrib, 8, 64);
    contrib += __shfl_xor(contrib, 4, 64);
    contrib += __shfl_xor(contrib, 2, 64);
    contrib += __shfl_xor(contrib, 1, 64);
    if (tid == 0) out[b] = contrib + bf0;
  }
  if (tid < NP) gw[(size_t)tid * NB + b] = wsum_s[tid];
}

// weights[i] = (1/256) * sum_{j<256} gw[(i>>1)*512 + (i&1)*256 + j]
__global__ __launch_bounds__(64, 1)
void pf_weights(const float* __restrict__ gw, float* __restrict__ out) {
  int i = blockIdx.x;
  int lane = threadIdx.x;
  const float* src = gw + ((size_t)(i >> 1)) * NB + (size_t)(i & 1) * NP;
  float4 v = ((const float4*)src)[lane];
  float s = (v.x + v.y) + (v.z + v.w);
  s += __shfl_xor(s, 32, 64);
  s += __shfl_xor(s, 16, 64);
  s += __shfl_xor(s, 8, 64);
  s += __shfl_xor(s, 4, 64);
  s += __shfl_xor(s, 2, 64);
  s += __shfl_xor(s, 1, 64);
  if (lane == 0) out[NB + i] = s * (1.0f / NP);
}

extern "C" void kernel_launch(void* const* d_in, const int* in_sizes, int n_in,
                              void* d_out, int out_size, void* d_ws, size_t ws_size,
                              hipStream_t stream) {
  (void)in_sizes; (void)n_in; (void)out_size; (void)ws_size;
  const float* input_data = (const float*)d_in[0];
  const float* y_prev     = (const float*)d_in[1];
  const float* Wv         = (const float*)d_in[2];
  const float* bv         = (const float*)d_in[3];
  const float* W_ih       = (const float*)d_in[4];
  const float* W_hh       = (const float*)d_in[5];
  const float* b_ih       = (const float*)d_in[6];
  const float* b_hh       = (const float*)d_in[7];
  const float* Wp         = (const float*)d_in[8];
  const float* bp         = (const float*)d_in[9];
  const float* Wf         = (const float*)d_in[10];
  const float* bf         = (const float*)d_in[11];
  float* out = (float*)d_out;
  float* gw  = (float*)d_ws;                           // [P][B] f32 = 512 KB
  float* cg  = gw + (size_t)NP * NB;                   // c state, 33.5 MB

  FKeys fk;
  for (int t = 0; t < NT; ++t) {
    uint32_t x0 = 0u, x1 = (uint32_t)t;
    threefry2x32(0u, 1234u, x0, x1);
    fk.a[t] = x0; fk.b[t] = x1;
  }

  pf_main<<<dim3(NB), dim3(NTHR), 0, stream>>>(
      input_data, y_prev, Wv, bv, W_ih, W_hh, b_ih, b_hh, Wp, bp, Wf, bf,
      out, gw, cg, fk);
  pf_weights<<<dim3(NB), dim3(64), 0, stream>>>(gw, out);
}

// Round 20
// 1245.191 us; speedup vs baseline: 1.0786x; 1.0727x over previous
//
#include <hip/hip_runtime.h>
#include <stdint.h>

#define NB 512   // batch
#define NT 32    // time steps
#define NIN 8    // input feats
#define NIN1 9   // + y_prev
#define NH 64    // hidden
#define NP 256   // particles
#define NTHR 512 // 8 waves: wave wq owns gate-rows r' in [32wq, 32wq+32)
#define HROW 68  // f16 row stride: 136 B = 34 dwords -> 2-way bank alias (free)

typedef __attribute__((ext_vector_type(8))) _Float16 f16x8;
typedef __attribute__((ext_vector_type(4))) float f32x4;

struct FKeys { uint32_t a[NT]; uint32_t b[NT]; };

// ---------------- Threefry-2x32-20 (exact JAX semantics) ----------------
__host__ __device__ __forceinline__ void tfr(uint32_t& x0, uint32_t& x1, int r) {
  x0 += x1; x1 = (x1 << r) | (x1 >> (32 - r)); x1 ^= x0;
}

__host__ __device__ __forceinline__ void threefry2x32(uint32_t k0, uint32_t k1,
                                                      uint32_t& x0, uint32_t& x1) {
  uint32_t k2 = k0 ^ k1 ^ 0x1BD11BDAu;
  x0 += k0; x1 += k1;
  tfr(x0,x1,13); tfr(x0,x1,15); tfr(x0,x1,26); tfr(x0,x1,6);
  x0 += k1; x1 += k2 + 1u;
  tfr(x0,x1,17); tfr(x0,x1,29); tfr(x0,x1,16); tfr(x0,x1,24);
  x0 += k2; x1 += k0 + 2u;
  tfr(x0,x1,13); tfr(x0,x1,15); tfr(x0,x1,26); tfr(x0,x1,6);
  x0 += k0; x1 += k1 + 3u;
  tfr(x0,x1,17); tfr(x0,x1,29); tfr(x0,x1,16); tfr(x0,x1,24);
  x0 += k1; x1 += k2 + 4u;
  tfr(x0,x1,13); tfr(x0,x1,15); tfr(x0,x1,26); tfr(x0,x1,6);
  x0 += k2; x1 += k0 + 5u;
}

// bits -> uniform -> sqrt(2)*erfinv  (XLA f32 path; __logf variant validated
// R11 at absmax 0.5).
__device__ __forceinline__ float normal_from_bits(uint32_t bits) {
  float f = __uint_as_float((bits >> 9) | 0x3f800000u) - 1.0f;
  const float lo = -0.99999994f;
  float u = fmaxf(lo, fmaf(f, 2.0f, lo));
  float w = -__logf(fmaf(-u, u, 1.0f));
  float p;
  if (w < 5.0f) {
    w -= 2.5f;
    p = 2.81022636e-08f;
    p = fmaf(p, w, 3.43273939e-07f);
    p = fmaf(p, w, -3.5233877e-06f);
    p = fmaf(p, w, -4.39150654e-06f);
    p = fmaf(p, w, 0.00021858087f);
    p = fmaf(p, w, -0.00125372503f);
    p = fmaf(p, w, -0.00417768164f);
    p = fmaf(p, w, 0.246640727f);
    p = fmaf(p, w, 1.50140941f);
  } else {
    w = sqrtf(w) - 3.0f;
    p = -0.000200214257f;
    p = fmaf(p, w, 0.000100950558f);
    p = fmaf(p, w, 0.00134934322f);
    p = fmaf(p, w, -0.00367342844f);
    p = fmaf(p, w, 0.00573950773f);
    p = fmaf(p, w, -0.0076224613f);
    p = fmaf(p, w, 0.00943887047f);
    p = fmaf(p, w, 1.00167406f);
    p = fmaf(p, w, 2.83297682f);
  }
  return 1.41421356f * (p * u);
}

__device__ __forceinline__ float frcp(float x) { return __builtin_amdgcn_rcpf(x); }
__device__ __forceinline__ float fsigmoid(float x) { return frcp(1.0f + __expf(-x)); }
__device__ __forceinline__ float ftanh(float x) { return 1.0f - 2.0f * frcp(1.0f + __expf(2.0f * x)); }

// f32 -> f16 bits (RNE)
__device__ __forceinline__ uint32_t pack_f16(float x) {
  union { _Float16 h; uint16_t u; } c;
  c.h = (_Float16)x;
  return (uint32_t)c.u;
}
__device__ __forceinline__ _Float16 bits_to_h(uint16_t u) {
  union { _Float16 h; uint16_t u; } c;
  c.u = u;
  return c.h;
}

// 8B-aligned LDS f16x8 load (two ds_read_b64)
__device__ __forceinline__ f16x8 ld8h(const _Float16* p) {
  union { f16x8 v; uint64_t q[2]; } u;
  u.q[0] = *(const uint64_t*)(p);
  u.q[1] = *(const uint64_t*)(p + 4);
  return u.v;
}

// ---------------- main kernel: one block (512 thr) per batch elem ----------------
// R19 structure EXACTLY (16x16x32 MFMA, single h1_s ~42 KB LDS, reg-staged new-h
// scatter, global f32 c), with __launch_bounds__(512, 4): 4 waves/SIMD minimum
// -> 128-reg total budget -> the HW can co-reside 2 blocks/CU. R19 needs only
// ~104 total regs, so the cap should not spill.
__global__ __launch_bounds__(NTHR, 4)
void pf_main(const float* __restrict__ input_data, const float* __restrict__ y_prev,
             const float* __restrict__ Wv, const float* __restrict__ bv,
             const float* __restrict__ W_ih, const float* __restrict__ W_hh,
             const float* __restrict__ b_ih, const float* __restrict__ b_hh,
             const float* __restrict__ Wp, const float* __restrict__ bp,
             const float* __restrict__ Wf, const float* __restrict__ bf,
             float* __restrict__ out, float* __restrict__ gw, float* __restrict__ cg,
             FKeys fk)
{
  __shared__ __align__(16) _Float16 h1_s[NP * HROW];  // 34.8 KB sorted h
  __shared__ __align__(16) float xg_s[NP];
  __shared__ __align__(16) float proj_s[NP];
  __shared__ float lp_s[NP];
  __shared__ float wsum_s[NP];
  __shared__ int   rankP_s[2 * NP];
  __shared__ float hsum_s[NH];
  __shared__ float std_s[NH];
  __shared__ float xs_s[16];

  const int tid  = threadIdx.x;
  const int b    = blockIdx.x;
  const int lane = tid & 63;
  const int wq   = tid >> 6;          // wave 0..7: gate-row group
  const int lrow = (lane >> 4) & 3;   // 0..3
  const int lcol = lane & 15;         // 0..15

  for (int i = tid; i < NP * HROW; i += NTHR) h1_s[i] = (_Float16)0.0f;
  if (tid < NP) wsum_s[tid] = 0.0f;
  if (tid < NH) hsum_s[tid] = 0.0f;

  const float bf0 = bf[0];
  const float bp0 = bp[0];
  const uint32_t bsh = (uint32_t)b << 6;

  // A fragments (single f16), loaded ONCE: w1f[kg2][kt]
  f16x8 w1f[2][2];
  #pragma unroll
  for (int kg2 = 0; kg2 < 2; ++kg2) {
    const int rpr  = 32 * wq + 16 * kg2 + lcol;
    const int orig = (rpr & 3) * NH + (rpr >> 2);
    #pragma unroll
    for (int kt = 0; kt < 2; ++kt) {
      #pragma unroll
      for (int e = 0; e < 8; ++e)
        w1f[kg2][kt][e] = (_Float16)W_hh[orig * NH + kt * 32 + lrow * 8 + e];
    }
  }

  float wf2[2], wp2[2];
  #pragma unroll
  for (int kg2 = 0; kg2 < 2; ++kg2) {
    const int k = 8 * wq + 4 * kg2 + lrow;
    wf2[kg2] = Wf[k];
    wp2[kg2] = Wp[k];
  }

  // global c base for this thread's wave group: cells addressed per (kg2, pt8, ab)
  float* cgw = cg + ((size_t)b * 8 + wq) * (2 * 8 * 128) + lane;

  auto finalize_init = [&]() {
    if (tid < NH) {
      float v = bv[tid];
      const float* wvr = Wv + tid * (NIN1 + NH);
      #pragma unroll
      for (int i = 0; i < NIN1; ++i) v = fmaf(xs_s[i], wvr[i], v);
      #pragma unroll
      for (int k = 0; k < NH; ++k)
        v = fmaf(hsum_s[k] * (1.0f / NP), wvr[NIN1 + k], v);
      std_s[tid] = fmaxf(v, 0.0f) + log1pf(expf(-fabsf(v)));   // softplus, libm exact
    }
    if (tid < NP) {
      const int orow = (tid & 3) * NH + (tid >> 2);
      float a = b_ih[orow] + b_hh[orow];
      const float* wr = W_ih + orow * NIN1;
      #pragma unroll
      for (int i = 0; i < NIN1; ++i) a = fmaf(xs_s[i], wr[i], a);
      xg_s[tid] = a;
      proj_s[tid] = bf0;
      float xp = bp0;
      #pragma unroll
      for (int i = 0; i < NIN1; ++i) xp = fmaf(xs_s[i], Wp[NH + i], xp);
      lp_s[tid] = xp;
    }
  };

  if (tid < NIN) xs_s[tid] = input_data[(b * NT + 0) * NIN + tid];
  if (tid == NIN) xs_s[NIN] = y_prev[b * NT + 0];
  __syncthreads();
  finalize_init();
  __syncthreads();

  for (int t = 0; t < NT; ++t) {
    // ================= phase A: MFMA + elementwise (+ xs_{t+1} prefetch) ========
    if (tid < 16 && t + 1 < NT) {
      if (tid < NIN) xs_s[tid] = input_data[(b * NT + t + 1) * NIN + tid];
      if (tid == NIN) xs_s[NIN] = y_prev[b * NT + t + 1];
    }

    float std2[2];
    #pragma unroll
    for (int kg2 = 0; kg2 < 2; ++kg2) std2[kg2] = std_s[8 * wq + 4 * kg2 + lrow];

    const uint32_t fk0 = fk.a[t], fk1 = fk.b[t];
    const bool t0 = (t == 0);
    float hs2[2] = {0.0f, 0.0f};
    uint32_t shp[2][8];   // packed new h: lo = (k,p), hi = (k,p+128)

    #pragma unroll
    for (int pt8 = 0; pt8 < 8; ++pt8) {
      const int p = 16 * pt8 + lcol;
      const f16x8 bA0 = ld8h(&h1_s[p * HROW + lrow * 8]);
      const f16x8 bA1 = ld8h(&h1_s[p * HROW + 32 + lrow * 8]);
      const f16x8 bB0 = ld8h(&h1_s[(p + 128) * HROW + lrow * 8]);
      const f16x8 bB1 = ld8h(&h1_s[(p + 128) * HROW + 32 + lrow * 8]);

      float plp = 0.0f, lpp = 0.0f, plp1 = 0.0f, lpp1 = 0.0f;
      #pragma unroll
      for (int kg2 = 0; kg2 < 2; ++kg2) {
        const int k = 8 * wq + 4 * kg2 + lrow;
        float* cptr = cgw + (size_t)(kg2 * 8 + pt8) * 128;
        const float cvA = cptr[0];
        const float cvB = cptr[64];
        const float4 xgv = *(const float4*)&xg_s[32 * wq + 16 * kg2 + 4 * lrow];
        f32x4 accA, accB;
        accA[0] = xgv.x; accA[1] = xgv.y; accA[2] = xgv.z; accA[3] = xgv.w;
        accB = accA;
        accA = __builtin_amdgcn_mfma_f32_16x16x32_f16(w1f[kg2][0], bA0, accA, 0, 0, 0);
        accB = __builtin_amdgcn_mfma_f32_16x16x32_f16(w1f[kg2][0], bB0, accB, 0, 0, 0);
        accA = __builtin_amdgcn_mfma_f32_16x16x32_f16(w1f[kg2][1], bA1, accA, 0, 0, 0);
        accB = __builtin_amdgcn_mfma_f32_16x16x32_f16(w1f[kg2][1], bB1, accB, 0, 0, 0);
        // ---- cell (k, p) ----
        float si = fsigmoid(accA[0]);
        float sf = fsigmoid(accA[1]);
        float so = fsigmoid(accA[3]);
        float cn = sf * (t0 ? 0.0f : cvA) + si * ftanh(accA[2]);
        cptr[0] = cn;
        float hlA = so * ftanh(cn);
        // ---- cell (k, p+128) ----
        float si2 = fsigmoid(accB[0]);
        float sf2 = fsigmoid(accB[1]);
        float so2 = fsigmoid(accB[3]);
        float cn2 = sf2 * (t0 ? 0.0f : cvB) + si2 * ftanh(accB[2]);
        cptr[64] = cn2;
        float hlB = so2 * ftanh(cn2);
        // ---- shared threefry: pair (p, p+128) ----
        uint32_t x0 = ((uint32_t)p << 15) | bsh | (uint32_t)k;
        uint32_t x1 = x0 + (1u << 22);
        threefry2x32(fk0, fk1, x0, x1);
        float hA = fmaf(normal_from_bits(x0), std2[kg2], hlA);
        float hB = fmaf(normal_from_bits(x1), std2[kg2], hlB);
        hs2[kg2] += hA + hB;
        plp  = fmaf(hA, wf2[kg2], plp);  lpp  = fmaf(hA, wp2[kg2], lpp);
        plp1 = fmaf(hB, wf2[kg2], plp1); lpp1 = fmaf(hB, wp2[kg2], lpp1);
        shp[kg2][pt8] = pack_f16(hA) | (pack_f16(hB) << 16);
      }
      // reduce over the 4 lrow groups sharing each particle column
      plp  += __shfl_xor(plp, 16, 64);  plp  += __shfl_xor(plp, 32, 64);
      lpp  += __shfl_xor(lpp, 16, 64);  lpp  += __shfl_xor(lpp, 32, 64);
      plp1 += __shfl_xor(plp1, 16, 64); plp1 += __shfl_xor(plp1, 32, 64);
      lpp1 += __shfl_xor(lpp1, 16, 64); lpp1 += __shfl_xor(lpp1, 32, 64);
      if (lane < 16) {
        atomicAdd(&proj_s[p], plp);
        atomicAdd(&lp_s[p], lpp);
        atomicAdd(&proj_s[p + 128], plp1);
        atomicAdd(&lp_s[p + 128], lpp1);
      }
    }
    // hsum: reduce over the 16 lcol lanes sharing each k
    #pragma unroll
    for (int kg2 = 0; kg2 < 2; ++kg2) {
      float s = hs2[kg2];
      s += __shfl_xor(s, 1, 64); s += __shfl_xor(s, 2, 64);
      s += __shfl_xor(s, 4, 64); s += __shfl_xor(s, 8, 64);
      if (lcol == 0) hsum_s[8 * wq + 4 * kg2 + lrow] = s;
    }
    __syncthreads();   // b1: h1 reads + proj/lp atomics + hsum + xs_next done

    // ================= phase R: split stable-rank (512 half-jobs) =================
    {
      const int ph = tid & (NP - 1);
      const int hh = tid >> 8;
      const float pv = proj_s[ph];
      int rk = 0;
      const float4* c4 = (const float4*)proj_s;
      #pragma unroll 8
      for (int q4 = 32 * hh; q4 < 32 * hh + 32; ++q4) {
        float4 v = c4[q4];
        int qb = q4 * 4;
        rk += (v.x < pv || (v.x == pv && qb + 0 < ph)) ? 1 : 0;
        rk += (v.y < pv || (v.y == pv && qb + 1 < ph)) ? 1 : 0;
        rk += (v.z < pv || (v.z == pv && qb + 2 < ph)) ? 1 : 0;
        rk += (v.w < pv || (v.w == pv && qb + 3 < ph)) ? 1 : 0;
      }
      rankP_s[hh * NP + ph] = rk;
    }
    __syncthreads();   // b2: rank partials ready

    // ================= phase F: scatter shp at ranked rows + wsum + next init ===
    if (tid < NP) {
      const int rank = rankP_s[tid] + rankP_s[NP + tid];
      wsum_s[rank] += __expf(lp_s[tid]);   // ranks form a permutation -> race-free
    }
    #pragma unroll
    for (int kg2 = 0; kg2 < 2; ++kg2) {
      const int k = 8 * wq + 4 * kg2 + lrow;
      #pragma unroll
      for (int pt8 = 0; pt8 < 8; ++pt8) {
        const int p = 16 * pt8 + lcol;
        const int rA = rankP_s[p] + rankP_s[NP + p];
        const int rB = rankP_s[p + 128] + rankP_s[NP + p + 128];
        const uint32_t v = shp[kg2][pt8];
        h1_s[rA * HROW + k] = bits_to_h((uint16_t)(v & 0xffffu));
        h1_s[rB * HROW + k] = bits_to_h((uint16_t)(v >> 16));
      }
    }
    finalize_init();
    __syncthreads();   // b3 (loop end): h writes + next-step init visible
  }

  // ---- epilogue: y_pred[b] = mean_p(h_fin) @ Wf + bf ----
  if (tid < NH) {
    float hm = hsum_s[tid] * (1.0f / NP);
    float contrib = hm * Wf[tid];
    contrib += __shfl_xor(contrib, 32, 64);
    contrib += __shfl_xor(contrib, 16, 64);
    contrib += __shfl_xor(contrib, 8, 64);
    contrib += __shfl_xor(contrib, 4, 64);
    contrib += __shfl_xor(contrib, 2, 64);
    contrib += __shfl_xor(contrib, 1, 64);
    if (tid == 0) out[b] = contrib + bf0;
  }
  if (tid < NP) gw[(size_t)tid * NB + b] = wsum_s[tid];
}

// weights[i] = (1/256) * sum_{j<256} gw[(i>>1)*512 + (i&1)*256 + j]
__global__ __launch_bounds__(64, 1)
void pf_weights(const float* __restrict__ gw, float* __restrict__ out) {
  int i = blockIdx.x;
  int lane = threadIdx.x;
  const float* src = gw + ((size_t)(i >> 1)) * NB + (size_t)(i & 1) * NP;
  float4 v = ((const float4*)src)[lane];
  float s = (v.x + v.y) + (v.z + v.w);
  s += __shfl_xor(s, 32, 64);
  s += __shfl_xor(s, 16, 64);
  s += __shfl_xor(s, 8, 64);
  s += __shfl_xor(s, 4, 64);
  s += __shfl_xor(s, 2, 64);
  s += __shfl_xor(s, 1, 64);
  if (lane == 0) out[NB + i] = s * (1.0f / NP);
}

extern "C" void kernel_launch(void* const* d_in, const int* in_sizes, int n_in,
                              void* d_out, int out_size, void* d_ws, size_t ws_size,
                              hipStream_t stream) {
  (void)in_sizes; (void)n_in; (void)out_size; (void)ws_size;
  const float* input_data = (const float*)d_in[0];
  const float* y_prev     = (const float*)d_in[1];
  const float* Wv         = (const float*)d_in[2];
  const float* bv         = (const float*)d_in[3];
  const float* W_ih       = (const float*)d_in[4];
  const float* W_hh       = (const float*)d_in[5];
  const float* b_ih       = (const float*)d_in[6];
  const float* b_hh       = (const float*)d_in[7];
  const float* Wp         = (const float*)d_in[8];
  const float* bp         = (const float*)d_in[9];
  const float* Wf         = (const float*)d_in[10];
  const float* bf         = (const float*)d_in[11];
  float* out = (float*)d_out;
  float* gw  = (float*)d_ws;                           // [P][B] f32 = 512 KB
  float* cg  = gw + (size_t)NP * NB;                   // c state, 33.5 MB

  FKeys fk;
  for (int t = 0; t < NT; ++t) {
    uint32_t x0 = 0u, x1 = (uint32_t)t;
    threefry2x32(0u, 1234u, x0, x1);
    fk.a[t] = x0; fk.b[t] = x1;
  }

  pf_main<<<dim3(NB), dim3(NTHR), 0, stream>>>(
      input_data, y_prev, Wv, bv, W_ih, W_hh, b_ih, b_hh, Wp, bp, Wf, bf,
      out, gw, cg, fk);
  pf_weights<<<dim3(NB), dim3(64), 0, stream>>>(gw, out);
}

// Round 21
// 1129.570 us; speedup vs baseline: 1.1890x; 1.1024x over previous
//
#include <hip/hip_runtime.h>
#include <stdint.h>

#define NB 512   // batch
#define NT 32    // time steps
#define NIN 8    // input feats
#define NIN1 9   // + y_prev
#define NH 64    // hidden
#define NP 256   // particles
#define NTHR 512 // 8 waves: wave wq owns gate-rows r' in [32wq, 32wq+32)
#define HROW 68  // f16 row stride: 136 B = 34 dwords -> 2-way bank alias (free)

typedef __attribute__((ext_vector_type(8))) _Float16 f16x8;
typedef __attribute__((ext_vector_type(4))) float f32x4;

struct FKeys { uint32_t a[NT]; uint32_t b[NT]; };

// ---------------- Threefry-2x32-20 (exact JAX semantics) ----------------
__host__ __device__ __forceinline__ void tfr(uint32_t& x0, uint32_t& x1, int r) {
  x0 += x1; x1 = (x1 << r) | (x1 >> (32 - r)); x1 ^= x0;
}

__host__ __device__ __forceinline__ void threefry2x32(uint32_t k0, uint32_t k1,
                                                      uint32_t& x0, uint32_t& x1) {
  uint32_t k2 = k0 ^ k1 ^ 0x1BD11BDAu;
  x0 += k0; x1 += k1;
  tfr(x0,x1,13); tfr(x0,x1,15); tfr(x0,x1,26); tfr(x0,x1,6);
  x0 += k1; x1 += k2 + 1u;
  tfr(x0,x1,17); tfr(x0,x1,29); tfr(x0,x1,16); tfr(x0,x1,24);
  x0 += k2; x1 += k0 + 2u;
  tfr(x0,x1,13); tfr(x0,x1,15); tfr(x0,x1,26); tfr(x0,x1,6);
  x0 += k0; x1 += k1 + 3u;
  tfr(x0,x1,17); tfr(x0,x1,29); tfr(x0,x1,16); tfr(x0,x1,24);
  x0 += k1; x1 += k2 + 4u;
  tfr(x0,x1,13); tfr(x0,x1,15); tfr(x0,x1,26); tfr(x0,x1,6);
  x0 += k2; x1 += k0 + 5u;
}

// bits -> uniform -> sqrt(2)*erfinv  (XLA f32 path; __logf variant validated
// R11 at absmax 0.5).
__device__ __forceinline__ float normal_from_bits(uint32_t bits) {
  float f = __uint_as_float((bits >> 9) | 0x3f800000u) - 1.0f;
  const float lo = -0.99999994f;
  float u = fmaxf(lo, fmaf(f, 2.0f, lo));
  float w = -__logf(fmaf(-u, u, 1.0f));
  float p;
  if (w < 5.0f) {
    w -= 2.5f;
    p = 2.81022636e-08f;
    p = fmaf(p, w, 3.43273939e-07f);
    p = fmaf(p, w, -3.5233877e-06f);
    p = fmaf(p, w, -4.39150654e-06f);
    p = fmaf(p, w, 0.00021858087f);
    p = fmaf(p, w, -0.00125372503f);
    p = fmaf(p, w, -0.00417768164f);
    p = fmaf(p, w, 0.246640727f);
    p = fmaf(p, w, 1.50140941f);
  } else {
    w = sqrtf(w) - 3.0f;
    p = -0.000200214257f;
    p = fmaf(p, w, 0.000100950558f);
    p = fmaf(p, w, 0.00134934322f);
    p = fmaf(p, w, -0.00367342844f);
    p = fmaf(p, w, 0.00573950773f);
    p = fmaf(p, w, -0.0076224613f);
    p = fmaf(p, w, 0.00943887047f);
    p = fmaf(p, w, 1.00167406f);
    p = fmaf(p, w, 2.83297682f);
  }
  return 1.41421356f * (p * u);
}

__device__ __forceinline__ float frcp(float x) { return __builtin_amdgcn_rcpf(x); }
__device__ __forceinline__ float fsigmoid(float x) { return frcp(1.0f + __expf(-x)); }
__device__ __forceinline__ float ftanh(float x) { return 1.0f - 2.0f * frcp(1.0f + __expf(2.0f * x)); }

// f32 -> f16 bits (RNE)
__device__ __forceinline__ uint32_t pack_f16(float x) {
  union { _Float16 h; uint16_t u; } c;
  c.h = (_Float16)x;
  return (uint32_t)c.u;
}
__device__ __forceinline__ _Float16 bits_to_h(uint16_t u) {
  union { _Float16 h; uint16_t u; } c;
  c.u = u;
  return c.h;
}

// 8B-aligned LDS f16x8 load (two ds_read_b64)
__device__ __forceinline__ f16x8 ld8h(const _Float16* p) {
  union { f16x8 v; uint64_t q[2]; } u;
  u.q[0] = *(const uint64_t*)(p);
  u.q[1] = *(const uint64_t*)(p + 4);
  return u.v;
}

// ---------------- main kernel: one block (512 thr) per batch elem ----------------
// R20 structure (16x16x32 MFMA, launch_bounds(512,4) -> 2 blocks/CU) with the
// c state moved from global f32 to LDS f16 (32 KB; lane-contiguous layout,
// conflict-free) — deletes ~2.2 GB of HBM c traffic. Total LDS ~74 KB/block,
// 2 blocks = ~149 KB <= 160.
__global__ __launch_bounds__(NTHR, 4)
void pf_main(const float* __restrict__ input_data, const float* __restrict__ y_prev,
             const float* __restrict__ Wv, const float* __restrict__ bv,
             const float* __restrict__ W_ih, const float* __restrict__ W_hh,
             const float* __restrict__ b_ih, const float* __restrict__ b_hh,
             const float* __restrict__ Wp, const float* __restrict__ bp,
             const float* __restrict__ Wf, const float* __restrict__ bf,
             float* __restrict__ out, float* __restrict__ gw,
             FKeys fk)
{
  __shared__ __align__(16) _Float16 h1_s[NP * HROW];  // 34.8 KB sorted h
  __shared__ __align__(16) _Float16 c_s[16384];       // 32 KB c state [wq][kg2][pt8][ab*64+lane]
  __shared__ __align__(16) float xg_s[NP];
  __shared__ __align__(16) float proj_s[NP];
  __shared__ float lp_s[NP];
  __shared__ float wsum_s[NP];
  __shared__ int   rankP_s[2 * NP];
  __shared__ float hsum_s[NH];
  __shared__ float std_s[NH];
  __shared__ float xs_s[16];

  const int tid  = threadIdx.x;
  const int b    = blockIdx.x;
  const int lane = tid & 63;
  const int wq   = tid >> 6;          // wave 0..7: gate-row group
  const int lrow = (lane >> 4) & 3;   // 0..3
  const int lcol = lane & 15;         // 0..15

  for (int i = tid; i < NP * HROW; i += NTHR) h1_s[i] = (_Float16)0.0f;
  for (int i = tid; i < 16384; i += NTHR) c_s[i] = (_Float16)0.0f;
  if (tid < NP) wsum_s[tid] = 0.0f;
  if (tid < NH) hsum_s[tid] = 0.0f;

  const float bf0 = bf[0];
  const float bp0 = bp[0];
  const uint32_t bsh = (uint32_t)b << 6;

  // A fragments (single f16), loaded ONCE: w1f[kg2][kt]
  f16x8 w1f[2][2];
  #pragma unroll
  for (int kg2 = 0; kg2 < 2; ++kg2) {
    const int rpr  = 32 * wq + 16 * kg2 + lcol;
    const int orig = (rpr & 3) * NH + (rpr >> 2);
    #pragma unroll
    for (int kt = 0; kt < 2; ++kt) {
      #pragma unroll
      for (int e = 0; e < 8; ++e)
        w1f[kg2][kt][e] = (_Float16)W_hh[orig * NH + kt * 32 + lrow * 8 + e];
    }
  }

  float wf2[2], wp2[2];
  #pragma unroll
  for (int kg2 = 0; kg2 < 2; ++kg2) {
    const int k = 8 * wq + 4 * kg2 + lrow;
    wf2[kg2] = Wf[k];
    wp2[kg2] = Wp[k];
  }

  // LDS c base for this thread: cells addressed per (kg2, pt8, ab)
  _Float16* cw = &c_s[wq * 2048 + lane];

  auto finalize_init = [&]() {
    if (tid < NH) {
      float v = bv[tid];
      const float* wvr = Wv + tid * (NIN1 + NH);
      #pragma unroll
      for (int i = 0; i < NIN1; ++i) v = fmaf(xs_s[i], wvr[i], v);
      #pragma unroll
      for (int k = 0; k < NH; ++k)
        v = fmaf(hsum_s[k] * (1.0f / NP), wvr[NIN1 + k], v);
      std_s[tid] = fmaxf(v, 0.0f) + log1pf(expf(-fabsf(v)));   // softplus, libm exact
    }
    if (tid < NP) {
      const int orow = (tid & 3) * NH + (tid >> 2);
      float a = b_ih[orow] + b_hh[orow];
      const float* wr = W_ih + orow * NIN1;
      #pragma unroll
      for (int i = 0; i < NIN1; ++i) a = fmaf(xs_s[i], wr[i], a);
      xg_s[tid] = a;
      proj_s[tid] = bf0;
      float xp = bp0;
      #pragma unroll
      for (int i = 0; i < NIN1; ++i) xp = fmaf(xs_s[i], Wp[NH + i], xp);
      lp_s[tid] = xp;
    }
  };

  if (tid < NIN) xs_s[tid] = input_data[(b * NT + 0) * NIN + tid];
  if (tid == NIN) xs_s[NIN] = y_prev[b * NT + 0];
  __syncthreads();
  finalize_init();
  __syncthreads();

  for (int t = 0; t < NT; ++t) {
    // ================= phase A: MFMA + elementwise (+ xs_{t+1} prefetch) ========
    if (tid < 16 && t + 1 < NT) {
      if (tid < NIN) xs_s[tid] = input_data[(b * NT + t + 1) * NIN + tid];
      if (tid == NIN) xs_s[NIN] = y_prev[b * NT + t + 1];
    }

    float std2[2];
    #pragma unroll
    for (int kg2 = 0; kg2 < 2; ++kg2) std2[kg2] = std_s[8 * wq + 4 * kg2 + lrow];

    const uint32_t fk0 = fk.a[t], fk1 = fk.b[t];
    float hs2[2] = {0.0f, 0.0f};
    uint32_t shp[2][8];   // packed new h: lo = (k,p), hi = (k,p+128)

    #pragma unroll
    for (int pt8 = 0; pt8 < 8; ++pt8) {
      const int p = 16 * pt8 + lcol;
      const f16x8 bA0 = ld8h(&h1_s[p * HROW + lrow * 8]);
      const f16x8 bA1 = ld8h(&h1_s[p * HROW + 32 + lrow * 8]);
      const f16x8 bB0 = ld8h(&h1_s[(p + 128) * HROW + lrow * 8]);
      const f16x8 bB1 = ld8h(&h1_s[(p + 128) * HROW + 32 + lrow * 8]);

      float plp = 0.0f, lpp = 0.0f, plp1 = 0.0f, lpp1 = 0.0f;
      #pragma unroll
      for (int kg2 = 0; kg2 < 2; ++kg2) {
        const int k = 8 * wq + 4 * kg2 + lrow;
        _Float16* cptr = cw + (kg2 * 8 + pt8) * 128;
        const float cvA = (float)cptr[0];
        const float cvB = (float)cptr[64];
        const float4 xgv = *(const float4*)&xg_s[32 * wq + 16 * kg2 + 4 * lrow];
        f32x4 accA, accB;
        accA[0] = xgv.x; accA[1] = xgv.y; accA[2] = xgv.z; accA[3] = xgv.w;
        accB = accA;
        accA = __builtin_amdgcn_mfma_f32_16x16x32_f16(w1f[kg2][0], bA0, accA, 0, 0, 0);
        accB = __builtin_amdgcn_mfma_f32_16x16x32_f16(w1f[kg2][0], bB0, accB, 0, 0, 0);
        accA = __builtin_amdgcn_mfma_f32_16x16x32_f16(w1f[kg2][1], bA1, accA, 0, 0, 0);
        accB = __builtin_amdgcn_mfma_f32_16x16x32_f16(w1f[kg2][1], bB1, accB, 0, 0, 0);
        // ---- cell (k, p) ----
        float si = fsigmoid(accA[0]);
        float sf = fsigmoid(accA[1]);
        float so = fsigmoid(accA[3]);
        float cn = sf * cvA + si * ftanh(accA[2]);
        cptr[0] = (_Float16)cn;
        float hlA = so * ftanh(cn);
        // ---- cell (k, p+128) ----
        float si2 = fsigmoid(accB[0]);
        float sf2 = fsigmoid(accB[1]);
        float so2 = fsigmoid(accB[3]);
        float cn2 = sf2 * cvB + si2 * ftanh(accB[2]);
        cptr[64] = (_Float16)cn2;
        float hlB = so2 * ftanh(cn2);
        // ---- shared threefry: pair (p, p+128) ----
        uint32_t x0 = ((uint32_t)p << 15) | bsh | (uint32_t)k;
        uint32_t x1 = x0 + (1u << 22);
        threefry2x32(fk0, fk1, x0, x1);
        float hA = fmaf(normal_from_bits(x0), std2[kg2], hlA);
        float hB = fmaf(normal_from_bits(x1), std2[kg2], hlB);
        hs2[kg2] += hA + hB;
        plp  = fmaf(hA, wf2[kg2], plp);  lpp  = fmaf(hA, wp2[kg2], lpp);
        plp1 = fmaf(hB, wf2[kg2], plp1); lpp1 = fmaf(hB, wp2[kg2], lpp1);
        shp[kg2][pt8] = pack_f16(hA) | (pack_f16(hB) << 16);
      }
      // reduce over the 4 lrow groups sharing each particle column
      plp  += __shfl_xor(plp, 16, 64);  plp  += __shfl_xor(plp, 32, 64);
      lpp  += __shfl_xor(lpp, 16, 64);  lpp  += __shfl_xor(lpp, 32, 64);
      plp1 += __shfl_xor(plp1, 16, 64); plp1 += __shfl_xor(plp1, 32, 64);
      lpp1 += __shfl_xor(lpp1, 16, 64); lpp1 += __shfl_xor(lpp1, 32, 64);
      if (lane < 16) {
        atomicAdd(&proj_s[p], plp);
        atomicAdd(&lp_s[p], lpp);
        atomicAdd(&proj_s[p + 128], plp1);
        atomicAdd(&lp_s[p + 128], lpp1);
      }
    }
    // hsum: reduce over the 16 lcol lanes sharing each k
    #pragma unroll
    for (int kg2 = 0; kg2 < 2; ++kg2) {
      float s = hs2[kg2];
      s += __shfl_xor(s, 1, 64); s += __shfl_xor(s, 2, 64);
      s += __shfl_xor(s, 4, 64); s += __shfl_xor(s, 8, 64);
      if (lcol == 0) hsum_s[8 * wq + 4 * kg2 + lrow] = s;
    }
    __syncthreads();   // b1: h1 reads + proj/lp atomics + hsum + xs_next done

    // ================= phase R: split stable-rank (512 half-jobs) =================
    {
      const int ph = tid & (NP - 1);
      const int hh = tid >> 8;
      const float pv = proj_s[ph];
      int rk = 0;
      const float4* c4 = (const float4*)proj_s;
      #pragma unroll 8
      for (int q4 = 32 * hh; q4 < 32 * hh + 32; ++q4) {
        float4 v = c4[q4];
        int qb = q4 * 4;
        rk += (v.x < pv || (v.x == pv && qb + 0 < ph)) ? 1 : 0;
        rk += (v.y < pv || (v.y == pv && qb + 1 < ph)) ? 1 : 0;
        rk += (v.z < pv || (v.z == pv && qb + 2 < ph)) ? 1 : 0;
        rk += (v.w < pv || (v.w == pv && qb + 3 < ph)) ? 1 : 0;
      }
      rankP_s[hh * NP + ph] = rk;
    }
    __syncthreads();   // b2: rank partials ready

    // ================= phase F: scatter shp at ranked rows + wsum + next init ===
    if (tid < NP) {
      const int rank = rankP_s[tid] + rankP_s[NP + tid];
      wsum_s[rank] += __expf(lp_s[tid]);   // ranks form a permutation -> race-free
    }
    #pragma unroll
    for (int kg2 = 0; kg2 < 2; ++kg2) {
      const int k = 8 * wq + 4 * kg2 + lrow;
      #pragma unroll
      for (int pt8 = 0; pt8 < 8; ++pt8) {
        const int p = 16 * pt8 + lcol;
        const int rA = rankP_s[p] + rankP_s[NP + p];
        const int rB = rankP_s[p + 128] + rankP_s[NP + p + 128];
        const uint32_t v = shp[kg2][pt8];
        h1_s[rA * HROW + k] = bits_to_h((uint16_t)(v & 0xffffu));
        h1_s[rB * HROW + k] = bits_to_h((uint16_t)(v >> 16));
      }
    }
    finalize_init();
    __syncthreads();   // b3 (loop end): h writes + next-step init visible
  }

  // ---- epilogue: y_pred[b] = mean_p(h_fin) @ Wf + bf ----
  if (tid < NH) {
    float hm = hsum_s[tid] * (1.0f / NP);
    float contrib = hm * Wf[tid];
    contrib += __shfl_xor(contrib, 32, 64);
    contrib += __shfl_xor(contrib, 16, 64);
    contrib += __shfl_xor(contrib, 8, 64);
    contrib += __shfl_xor(contrib, 4, 64);
    contrib += __shfl_xor(contrib, 2, 64);
    contrib += __shfl_xor(contrib, 1, 64);
    if (tid == 0) out[b] = contrib + bf0;
  }
  if (tid < NP) gw[(size_t)tid * NB + b] = wsum_s[tid];
}

// weights[i] = (1/256) * sum_{j<256} gw[(i>>1)*512 + (i&1)*256 + j]
__global__ __launch_bounds__(64, 1)
void pf_weights(const float* __restrict__ gw, float* __restrict__ out) {
  int i = blockIdx.x;
  int lane = threadIdx.x;
  const float* src = gw + ((size_t)(i >> 1)) * NB + (size_t)(i & 1) * NP;
  float4 v = ((const float4*)src)[lane];
  float s = (v.x + v.y) + (v.z + v.w);
  s += __shfl_xor(s, 32, 64);
  s += __shfl_xor(s, 16, 64);
  s += __shfl_xor(s, 8, 64);
  s += __shfl_xor(s, 4, 64);
  s += __shfl_xor(s, 2, 64);
  s += __shfl_xor(s, 1, 64);
  if (lane == 0) out[NB + i] = s * (1.0f / NP);
}

extern "C" void kernel_launch(void* const* d_in, const int* in_sizes, int n_in,
                              void* d_out, int out_size, void* d_ws, size_t ws_size,
                              hipStream_t stream) {
  (void)in_sizes; (void)n_in; (void)out_size; (void)ws_size;
  const float* input_data = (const float*)d_in[0];
  const float* y_prev     = (const float*)d_in[1];
  const float* Wv         = (const float*)d_in[2];
  const float* bv         = (const float*)d_in[3];
  const float* W_ih       = (const float*)d_in[4];
  const float* W_hh       = (const float*)d_in[5];
  const float* b_ih       = (const float*)d_in[6];
  const float* b_hh       = (const float*)d_in[7];
  const float* Wp         = (const float*)d_in[8];
  const float* bp         = (const float*)d_in[9];
  const float* Wf         = (const float*)d_in[10];
  const float* bf         = (const float*)d_in[11];
  float* out = (float*)d_out;
  float* gw  = (float*)d_ws;                           // [P][B] f32 = 512 KB

  FKeys fk;
  for (int t = 0; t < NT; ++t) {
    uint32_t x0 = 0u, x1 = (uint32_t)t;
    threefry2x32(0u, 1234u, x0, x1);
    fk.a[t] = x0; fk.b[t] = x1;
  }

  pf_main<<<dim3(NB), dim3(NTHR), 0, stream>>>(
      input_data, y_prev, Wv, bv, W_ih, W_hh, b_ih, b_hh, Wp, bp, Wf, bf,
      out, gw, fk);
  pf_weights<<<dim3(NB), dim3(64), 0, stream>>>(gw, out);
}

// Round 22
// 1128.011 us; speedup vs baseline: 1.1906x; 1.0014x over previous
//
#include <hip/hip_runtime.h>
#include <stdint.h>

#define NB 512   // batch
#define NT 32    // time steps
#define NIN 8    // input feats
#define NIN1 9   // + y_prev
#define NH 64    // hidden
#define NP 256   // particles
#define NTHR 512 // 8 waves: wave wq owns gate-rows r' in [32wq, 32wq+32)
#define HROW 68  // f16 row stride: 136 B = 34 dwords -> 2-way bank alias (free)

typedef __attribute__((ext_vector_type(8))) _Float16 f16x8;
typedef __attribute__((ext_vector_type(4))) float f32x4;

struct FKeys { uint32_t a[NT]; uint32_t b[NT]; };

// ---------------- Threefry-2x32-20 (exact JAX semantics) ----------------
__host__ __device__ __forceinline__ void tfr(uint32_t& x0, uint32_t& x1, int r) {
  x0 += x1; x1 = (x1 << r) | (x1 >> (32 - r)); x1 ^= x0;
}

__host__ __device__ __forceinline__ void threefry2x32(uint32_t k0, uint32_t k1,
                                                      uint32_t& x0, uint32_t& x1) {
  uint32_t k2 = k0 ^ k1 ^ 0x1BD11BDAu;
  x0 += k0; x1 += k1;
  tfr(x0,x1,13); tfr(x0,x1,15); tfr(x0,x1,26); tfr(x0,x1,6);
  x0 += k1; x1 += k2 + 1u;
  tfr(x0,x1,17); tfr(x0,x1,29); tfr(x0,x1,16); tfr(x0,x1,24);
  x0 += k2; x1 += k0 + 2u;
  tfr(x0,x1,13); tfr(x0,x1,15); tfr(x0,x1,26); tfr(x0,x1,6);
  x0 += k0; x1 += k1 + 3u;
  tfr(x0,x1,17); tfr(x0,x1,29); tfr(x0,x1,16); tfr(x0,x1,24);
  x0 += k1; x1 += k2 + 4u;
  tfr(x0,x1,13); tfr(x0,x1,15); tfr(x0,x1,26); tfr(x0,x1,6);
  x0 += k2; x1 += k0 + 5u;
}

// bits -> uniform -> sqrt(2)*erfinv  (XLA f32 path; __logf variant validated
// R11 at absmax 0.5).
__device__ __forceinline__ float normal_from_bits(uint32_t bits) {
  float f = __uint_as_float((bits >> 9) | 0x3f800000u) - 1.0f;
  const float lo = -0.99999994f;
  float u = fmaxf(lo, fmaf(f, 2.0f, lo));
  float w = -__logf(fmaf(-u, u, 1.0f));
  float p;
  if (w < 5.0f) {
    w -= 2.5f;
    p = 2.81022636e-08f;
    p = fmaf(p, w, 3.43273939e-07f);
    p = fmaf(p, w, -3.5233877e-06f);
    p = fmaf(p, w, -4.39150654e-06f);
    p = fmaf(p, w, 0.00021858087f);
    p = fmaf(p, w, -0.00125372503f);
    p = fmaf(p, w, -0.00417768164f);
    p = fmaf(p, w, 0.246640727f);
    p = fmaf(p, w, 1.50140941f);
  } else {
    w = sqrtf(w) - 3.0f;
    p = -0.000200214257f;
    p = fmaf(p, w, 0.000100950558f);
    p = fmaf(p, w, 0.00134934322f);
    p = fmaf(p, w, -0.00367342844f);
    p = fmaf(p, w, 0.00573950773f);
    p = fmaf(p, w, -0.0076224613f);
    p = fmaf(p, w, 0.00943887047f);
    p = fmaf(p, w, 1.00167406f);
    p = fmaf(p, w, 2.83297682f);
  }
  return 1.41421356f * (p * u);
}

__device__ __forceinline__ float frcp(float x) { return __builtin_amdgcn_rcpf(x); }
__device__ __forceinline__ float fsigmoid(float x) { return frcp(1.0f + __expf(-x)); }
__device__ __forceinline__ float ftanh(float x) { return 1.0f - 2.0f * frcp(1.0f + __expf(2.0f * x)); }

// f32 -> f16 bits (RNE)
__device__ __forceinline__ uint32_t pack_f16(float x) {
  union { _Float16 h; uint16_t u; } c;
  c.h = (_Float16)x;
  return (uint32_t)c.u;
}
__device__ __forceinline__ _Float16 bits_to_h(uint16_t u) {
  union { _Float16 h; uint16_t u; } c;
  c.u = u;
  return c.h;
}
__device__ __forceinline__ float f16_lo(uint32_t w) {
  union { _Float16 h; uint16_t u; } c; c.u = (uint16_t)(w & 0xffffu); return (float)c.h;
}
__device__ __forceinline__ float f16_hi(uint32_t w) {
  union { _Float16 h; uint16_t u; } c; c.u = (uint16_t)(w >> 16); return (float)c.h;
}

// 8B-aligned LDS f16x8 load (two ds_read_b64)
__device__ __forceinline__ f16x8 ld8h(const _Float16* p) {
  union { f16x8 v; uint64_t q[2]; } u;
  u.q[0] = *(const uint64_t*)(p);
  u.q[1] = *(const uint64_t*)(p + 4);
  return u.v;
}

// ---------------- eps precompute: one thread per threefry pair ----------------
// packed u32 (epsA | epsB<<16) at linear idx g = (b<<18)|(t<<13)|(k<<7)|pp.
__global__ __launch_bounds__(256)
void pf_eps(uint32_t* __restrict__ eps, FKeys fk) {
  const uint32_t g  = blockIdx.x * 256u + threadIdx.x;
  const uint32_t pp = g & 127u;
  const uint32_t k  = (g >> 7) & 63u;
  const uint32_t t  = (g >> 13) & 31u;
  const uint32_t b  = g >> 18;
  uint32_t x0 = (pp << 15) | (b << 6) | k;
  uint32_t x1 = x0 + (1u << 22);
  threefry2x32(fk.a[t], fk.b[t], x0, x1);
  eps[g] = pack_f16(normal_from_bits(x0)) | (pack_f16(normal_from_bits(x1)) << 16);
}

// ---------------- main kernel: one block (512 thr) per batch elem ----------------
// R21 structure (16x16x32 MFMA, launch_bounds(512,4), LDS f16 c, reg-staged
// scatter). USE_EPS: threefry+erfinv replaced by 16 coalesced u32 loads of
// precomputed f16 eps pairs, prefetched at step start (latency hides under
// the pt8 MFMA chains).
template <bool USE_EPS>
__global__ __launch_bounds__(NTHR, 4)
void pf_main(const float* __restrict__ input_data, const float* __restrict__ y_prev,
             const float* __restrict__ Wv, const float* __restrict__ bv,
             const float* __restrict__ W_ih, const float* __restrict__ W_hh,
             const float* __restrict__ b_ih, const float* __restrict__ b_hh,
             const float* __restrict__ Wp, const float* __restrict__ bp,
             const float* __restrict__ Wf, const float* __restrict__ bf,
             float* __restrict__ out, float* __restrict__ gw,
             const uint32_t* __restrict__ eps, FKeys fk)
{
  __shared__ __align__(16) _Float16 h1_s[NP * HROW];  // 34.8 KB sorted h
  __shared__ __align__(16) _Float16 c_s[16384];       // 32 KB c state
  __shared__ __align__(16) float xg_s[NP];
  __shared__ __align__(16) float proj_s[NP];
  __shared__ float lp_s[NP];
  __shared__ float wsum_s[NP];
  __shared__ int   rankP_s[2 * NP];
  __shared__ float hsum_s[NH];
  __shared__ float std_s[NH];
  __shared__ float xs_s[16];

  const int tid  = threadIdx.x;
  const int b    = blockIdx.x;
  const int lane = tid & 63;
  const int wq   = tid >> 6;          // wave 0..7: gate-row group
  const int lrow = (lane >> 4) & 3;   // 0..3
  const int lcol = lane & 15;         // 0..15

  for (int i = tid; i < NP * HROW; i += NTHR) h1_s[i] = (_Float16)0.0f;
  for (int i = tid; i < 16384; i += NTHR) c_s[i] = (_Float16)0.0f;
  if (tid < NP) wsum_s[tid] = 0.0f;
  if (tid < NH) hsum_s[tid] = 0.0f;

  const float bf0 = bf[0];
  const float bp0 = bp[0];
  const uint32_t bsh = (uint32_t)b << 6;

  // A fragments (single f16), loaded ONCE: w1f[kg2][kt]
  f16x8 w1f[2][2];
  #pragma unroll
  for (int kg2 = 0; kg2 < 2; ++kg2) {
    const int rpr  = 32 * wq + 16 * kg2 + lcol;
    const int orig = (rpr & 3) * NH + (rpr >> 2);
    #pragma unroll
    for (int kt = 0; kt < 2; ++kt) {
      #pragma unroll
      for (int e = 0; e < 8; ++e)
        w1f[kg2][kt][e] = (_Float16)W_hh[orig * NH + kt * 32 + lrow * 8 + e];
    }
  }

  float wf2[2], wp2[2];
  #pragma unroll
  for (int kg2 = 0; kg2 < 2; ++kg2) {
    const int k = 8 * wq + 4 * kg2 + lrow;
    wf2[kg2] = Wf[k];
    wp2[kg2] = Wp[k];
  }

  // LDS c base for this thread: cells addressed per (kg2, pt8, ab)
  _Float16* cw = &c_s[wq * 2048 + lane];

  auto finalize_init = [&]() {
    if (tid < NH) {
      float v = bv[tid];
      const float* wvr = Wv + tid * (NIN1 + NH);
      #pragma unroll
      for (int i = 0; i < NIN1; ++i) v = fmaf(xs_s[i], wvr[i], v);
      #pragma unroll
      for (int k = 0; k < NH; ++k)
        v = fmaf(hsum_s[k] * (1.0f / NP), wvr[NIN1 + k], v);
      std_s[tid] = fmaxf(v, 0.0f) + log1pf(expf(-fabsf(v)));   // softplus, libm exact
    }
    if (tid < NP) {
      const int orow = (tid & 3) * NH + (tid >> 2);
      float a = b_ih[orow] + b_hh[orow];
      const float* wr = W_ih + orow * NIN1;
      #pragma unroll
      for (int i = 0; i < NIN1; ++i) a = fmaf(xs_s[i], wr[i], a);
      xg_s[tid] = a;
      proj_s[tid] = bf0;
      float xp = bp0;
      #pragma unroll
      for (int i = 0; i < NIN1; ++i) xp = fmaf(xs_s[i], Wp[NH + i], xp);
      lp_s[tid] = xp;
    }
  };

  if (tid < NIN) xs_s[tid] = input_data[(b * NT + 0) * NIN + tid];
  if (tid == NIN) xs_s[NIN] = y_prev[b * NT + 0];
  __syncthreads();
  finalize_init();
  __syncthreads();

  for (int t = 0; t < NT; ++t) {
    // ================= phase A: MFMA + elementwise (+ xs_{t+1} prefetch) ========
    if (tid < 16 && t + 1 < NT) {
      if (tid < NIN) xs_s[tid] = input_data[(b * NT + t + 1) * NIN + tid];
      if (tid == NIN) xs_s[NIN] = y_prev[b * NT + t + 1];
    }

    float std2[2];
    #pragma unroll
    for (int kg2 = 0; kg2 < 2; ++kg2) std2[kg2] = std_s[8 * wq + 4 * kg2 + lrow];

    const uint32_t fk0 = fk.a[t], fk1 = fk.b[t];
    float hs2[2] = {0.0f, 0.0f};
    uint32_t shp[2][8];   // packed new h: lo = (k,p), hi = (k,p+128)

    // prefetch all 16 eps pairs for this step (coalesced 64B segments per lrow)
    uint32_t epsr[16];
    if constexpr (USE_EPS) {
      const uint32_t* epst = eps + ((size_t)(b * NT + t) << 13);
      #pragma unroll
      for (int kg2 = 0; kg2 < 2; ++kg2) {
        const int k = 8 * wq + 4 * kg2 + lrow;
        #pragma unroll
        for (int pt8 = 0; pt8 < 8; ++pt8)
          epsr[kg2 * 8 + pt8] = epst[k * 128 + 16 * pt8 + lcol];
      }
    }

    #pragma unroll
    for (int pt8 = 0; pt8 < 8; ++pt8) {
      const int p = 16 * pt8 + lcol;
      const f16x8 bA0 = ld8h(&h1_s[p * HROW + lrow * 8]);
      const f16x8 bA1 = ld8h(&h1_s[p * HROW + 32 + lrow * 8]);
      const f16x8 bB0 = ld8h(&h1_s[(p + 128) * HROW + lrow * 8]);
      const f16x8 bB1 = ld8h(&h1_s[(p + 128) * HROW + 32 + lrow * 8]);

      float plp = 0.0f, lpp = 0.0f, plp1 = 0.0f, lpp1 = 0.0f;
      #pragma unroll
      for (int kg2 = 0; kg2 < 2; ++kg2) {
        const int k = 8 * wq + 4 * kg2 + lrow;
        _Float16* cptr = cw + (kg2 * 8 + pt8) * 128;
        const float cvA = (float)cptr[0];
        const float cvB = (float)cptr[64];
        const float4 xgv = *(const float4*)&xg_s[32 * wq + 16 * kg2 + 4 * lrow];
        f32x4 accA, accB;
        accA[0] = xgv.x; accA[1] = xgv.y; accA[2] = xgv.z; accA[3] = xgv.w;
        accB = accA;
        accA = __builtin_amdgcn_mfma_f32_16x16x32_f16(w1f[kg2][0], bA0, accA, 0, 0, 0);
        accB = __builtin_amdgcn_mfma_f32_16x16x32_f16(w1f[kg2][0], bB0, accB, 0, 0, 0);
        accA = __builtin_amdgcn_mfma_f32_16x16x32_f16(w1f[kg2][1], bA1, accA, 0, 0, 0);
        accB = __builtin_amdgcn_mfma_f32_16x16x32_f16(w1f[kg2][1], bB1, accB, 0, 0, 0);
        // ---- cell (k, p) ----
        float si = fsigmoid(accA[0]);
        float sf = fsigmoid(accA[1]);
        float so = fsigmoid(accA[3]);
        float cn = sf * cvA + si * ftanh(accA[2]);
        cptr[0] = (_Float16)cn;
        float hlA = so * ftanh(cn);
        // ---- cell (k, p+128) ----
        float si2 = fsigmoid(accB[0]);
        float sf2 = fsigmoid(accB[1]);
        float so2 = fsigmoid(accB[3]);
        float cn2 = sf2 * cvB + si2 * ftanh(accB[2]);
        cptr[64] = (_Float16)cn2;
        float hlB = so2 * ftanh(cn2);
        // ---- eps: precomputed pair or inline threefry ----
        float eA, eB;
        if constexpr (USE_EPS) {
          const uint32_t ev = epsr[kg2 * 8 + pt8];
          eA = f16_lo(ev);
          eB = f16_hi(ev);
        } else {
          uint32_t x0 = ((uint32_t)p << 15) | bsh | (uint32_t)k;
          uint32_t x1 = x0 + (1u << 22);
          threefry2x32(fk0, fk1, x0, x1);
          eA = normal_from_bits(x0);
          eB = normal_from_bits(x1);
        }
        float hA = fmaf(eA, std2[kg2], hlA);
        float hB = fmaf(eB, std2[kg2], hlB);
        hs2[kg2] += hA + hB;
        plp  = fmaf(hA, wf2[kg2], plp);  lpp  = fmaf(hA, wp2[kg2], lpp);
        plp1 = fmaf(hB, wf2[kg2], plp1); lpp1 = fmaf(hB, wp2[kg2], lpp1);
        shp[kg2][pt8] = pack_f16(hA) | (pack_f16(hB) << 16);
      }
      // reduce over the 4 lrow groups sharing each particle column
      plp  += __shfl_xor(plp, 16, 64);  plp  += __shfl_xor(plp, 32, 64);
      lpp  += __shfl_xor(lpp, 16, 64);  lpp  += __shfl_xor(lpp, 32, 64);
      plp1 += __shfl_xor(plp1, 16, 64); plp1 += __shfl_xor(plp1, 32, 64);
      lpp1 += __shfl_xor(lpp1, 16, 64); lpp1 += __shfl_xor(lpp1, 32, 64);
      if (lane < 16) {
        atomicAdd(&proj_s[p], plp);
        atomicAdd(&lp_s[p], lpp);
        atomicAdd(&proj_s[p + 128], plp1);
        atomicAdd(&lp_s[p + 128], lpp1);
      }
    }
    // hsum: reduce over the 16 lcol lanes sharing each k
    #pragma unroll
    for (int kg2 = 0; kg2 < 2; ++kg2) {
      float s = hs2[kg2];
      s += __shfl_xor(s, 1, 64); s += __shfl_xor(s, 2, 64);
      s += __shfl_xor(s, 4, 64); s += __shfl_xor(s, 8, 64);
      if (lcol == 0) hsum_s[8 * wq + 4 * kg2 + lrow] = s;
    }
    __syncthreads();   // b1: h1 reads + proj/lp atomics + hsum + xs_next done

    // ================= phase R: split stable-rank (512 half-jobs) =================
    {
      const int ph = tid & (NP - 1);
      const int hh = tid >> 8;
      const float pv = proj_s[ph];
      int rk = 0;
      const float4* c4 = (const float4*)proj_s;
      #pragma unroll 8
      for (int q4 = 32 * hh; q4 < 32 * hh + 32; ++q4) {
        float4 v = c4[q4];
        int qb = q4 * 4;
        rk += (v.x < pv || (v.x == pv && qb + 0 < ph)) ? 1 : 0;
        rk += (v.y < pv || (v.y == pv && qb + 1 < ph)) ? 1 : 0;
        rk += (v.z < pv || (v.z == pv && qb + 2 < ph)) ? 1 : 0;
        rk += (v.w < pv || (v.w == pv && qb + 3 < ph)) ? 1 : 0;
      }
      rankP_s[hh * NP + ph] = rk;
    }
    __syncthreads();   // b2: rank partials ready

    // ================= phase F: scatter shp at ranked rows + wsum + next init ===
    if (tid < NP) {
      const int rank = rankP_s[tid] + rankP_s[NP + tid];
      wsum_s[rank] += __expf(lp_s[tid]);   // ranks form a permutation -> race-free
    }
    #pragma unroll
    for (int kg2 = 0; kg2 < 2; ++kg2) {
      const int k = 8 * wq + 4 * kg2 + lrow;
      #pragma unroll
      for (int pt8 = 0; pt8 < 8; ++pt8) {
        const int p = 16 * pt8 + lcol;
        const int rA = rankP_s[p] + rankP_s[NP + p];
        const int rB = rankP_s[p + 128] + rankP_s[NP + p + 128];
        const uint32_t v = shp[kg2][pt8];
        h1_s[rA * HROW + k] = bits_to_h((uint16_t)(v & 0xffffu));
        h1_s[rB * HROW + k] = bits_to_h((uint16_t)(v >> 16));
      }
    }
    finalize_init();
    __syncthreads();   // b3 (loop end): h writes + next-step init visible
  }

  // ---- epilogue: y_pred[b] = mean_p(h_fin) @ Wf + bf ----
  if (tid < NH) {
    float hm = hsum_s[tid] * (1.0f / NP);
    float contrib = hm * Wf[tid];
    contrib += __shfl_xor(contrib, 32, 64);
    contrib += __shfl_xor(contrib, 16, 64);
    contrib += __shfl_xor(contrib, 8, 64);
    contrib += __shfl_xor(contrib, 4, 64);
    contrib += __shfl_xor(contrib, 2, 64);
    contrib += __shfl_xor(contrib, 1, 64);
    if (tid == 0) out[b] = contrib + bf0;
  }
  if (tid < NP) gw[(size_t)tid * NB + b] = wsum_s[tid];
}

// weights[i] = (1/256) * sum_{j<256} gw[(i>>1)*512 + (i&1)*256 + j]
__global__ __launch_bounds__(64, 1)
void pf_weights(const float* __restrict__ gw, float* __restrict__ out) {
  int i = blockIdx.x;
  int lane = threadIdx.x;
  const float* src = gw + ((size_t)(i >> 1)) * NB + (size_t)(i & 1) * NP;
  float4 v = ((const float4*)src)[lane];
  float s = (v.x + v.y) + (v.z + v.w);
  s += __shfl_xor(s, 32, 64);
  s += __shfl_xor(s, 16, 64);
  s += __shfl_xor(s, 8, 64);
  s += __shfl_xor(s, 4, 64);
  s += __shfl_xor(s, 2, 64);
  s += __shfl_xor(s, 1, 64);
  if (lane == 0) out[NB + i] = s * (1.0f / NP);
}

extern "C" void kernel_launch(void* const* d_in, const int* in_sizes, int n_in,
                              void* d_out, int out_size, void* d_ws, size_t ws_size,
                              hipStream_t stream) {
  (void)in_sizes; (void)n_in; (void)out_size;
  const float* input_data = (const float*)d_in[0];
  const float* y_prev     = (const float*)d_in[1];
  const float* Wv         = (const float*)d_in[2];
  const float* bv         = (const float*)d_in[3];
  const float* W_ih       = (const float*)d_in[4];
  const float* W_hh       = (const float*)d_in[5];
  const float* b_ih       = (const float*)d_in[6];
  const float* b_hh       = (const float*)d_in[7];
  const float* Wp         = (const float*)d_in[8];
  const float* bp         = (const float*)d_in[9];
  const float* Wf         = (const float*)d_in[10];
  const float* bf         = (const float*)d_in[11];
  float* out = (float*)d_out;
  float* gw  = (float*)d_ws;                           // [P][B] f32 = 512 KB

  FKeys fk;
  for (int t = 0; t < NT; ++t) {
    uint32_t x0 = 0u, x1 = (uint32_t)t;
    threefry2x32(0u, 1234u, x0, x1);
    fk.a[t] = x0; fk.b[t] = x1;
  }

  const size_t gw_bytes  = (size_t)NP * NB * sizeof(float);
  const size_t eps_elems = (size_t)NB * NT * NH * 128;   // packed pairs
  const size_t need      = gw_bytes + eps_elems * sizeof(uint32_t);  // ~537.4 MB

  if (ws_size >= need) {
    uint32_t* eps = (uint32_t*)(gw + (size_t)NP * NB);
    pf_eps<<<dim3((unsigned)(eps_elems / 256)), dim3(256), 0, stream>>>(eps, fk);
    pf_main<true><<<dim3(NB), dim3(NTHR), 0, stream>>>(
        input_data, y_prev, Wv, bv, W_ih, W_hh, b_ih, b_hh, Wp, bp, Wf, bf,
        out, gw, eps, fk);
  } else {
    pf_main<false><<<dim3(NB), dim3(NTHR), 0, stream>>>(
        input_data, y_prev, Wv, bv, W_ih, W_hh, b_ih, b_hh, Wp, bp, Wf, bf,
        out, gw, nullptr, fk);
  }
  pf_weights<<<dim3(NB), dim3(64), 0, stream>>>(gw, out);
}